// Round 4
// baseline (561.876 us; speedup 1.0000x reference)
//
#include <hip/hip_runtime.h>
#include <cstdint>

#define SEQ    2048
#define DM     512
#define DAUX   64

typedef _Float16 f16;
typedef __attribute__((ext_vector_type(2))) _Float16 f16x2;
typedef __attribute__((ext_vector_type(4))) _Float16 f16x4;
typedef __attribute__((ext_vector_type(8))) _Float16 f16x8;
typedef __attribute__((ext_vector_type(4))) float fx4;
typedef __attribute__((ext_vector_type(16))) float fx16;

// async global->LDS, 16B per lane. LDS dest must be wave-uniform base + lane*16.
__device__ __forceinline__ void g2l16(const void* g, void* l) {
  __builtin_amdgcn_global_load_lds(
      (__attribute__((address_space(1))) void*)const_cast<void*>(g),
      (__attribute__((address_space(3))) void*)l, 16, 0, 0);
}

// raw sync primitives for the counted-vmcnt pipeline (T4): never drain vmcnt
// to 0 at a main-loop barrier; keep 8 loads (2 chunks) in flight.
#define WAITV8 { asm volatile("s_waitcnt vmcnt(8)" ::: "memory"); __builtin_amdgcn_sched_barrier(0); }
#define WAITV4 { asm volatile("s_waitcnt vmcnt(4)" ::: "memory"); __builtin_amdgcn_sched_barrier(0); }
#define WAITV0 { asm volatile("s_waitcnt vmcnt(0)" ::: "memory"); __builtin_amdgcn_sched_barrier(0); }
#define WAITL0 { asm volatile("s_waitcnt lgkmcnt(0)" ::: "memory"); __builtin_amdgcn_sched_barrier(0); }
#define BAR __builtin_amdgcn_s_barrier()

// ---- BK=32 tile [128][32], XOR swizzle on 8-elem blocks (jp ^ (row>>1)&3).
__device__ __forceinline__ void stage32(const f16* __restrict__ g0, int stride,
                                        f16* lds, int t) {
#pragma unroll
  for (int p = 0; p < 2; ++p) {
    int L = p * 256 + t;          // 0..511
    int row = L >> 2;             // 0..127
    int jp = L & 3;
    int jl = jp ^ ((row >> 1) & 3);
    g2l16(g0 + (size_t)row * stride + jl * 8, lds + L * 8);
  }
}
__device__ __forceinline__ f16x8 frag32(const f16* lds, int row, int kq) {
  int jp = (kq >> 3) ^ ((row >> 1) & 3);
  return *(const f16x8*)(lds + row * 32 + jp * 8);
}

// ---- BK=64 tile [128][64], swizzle jp ^ (row&7) (measured conflict-free).
__device__ __forceinline__ void stage64(const f16* __restrict__ g0, int stride,
                                        f16* lds, int t) {
#pragma unroll
  for (int p = 0; p < 4; ++p) {
    int L = p * 256 + t;          // 0..1023
    int row = L >> 3;
    int jp = L & 7;
    int jl = jp ^ (row & 7);
    g2l16(g0 + (size_t)row * stride + jl * 8, lds + L * 8);
  }
}
__device__ __forceinline__ f16x8 frag64(const f16* lds, int row, int kq) {
  int jp = (kq >> 3) ^ (row & 7);
  return *(const f16x8*)(lds + row * 64 + jp * 8);
}

// ---- BK=16 tile [128][16] (4 KB/array). XOR swizzle jl = jp ^ ((row>>2)&1).
__device__ __forceinline__ f16x8 frag16(const f16* lds, int row, int kq) {
  int jp = (kq >> 3) ^ ((row >> 2) & 1);
  return *(const f16x8*)(lds + row * 16 + jp * 8);
}

// stage one BK=16 chunk of all 4 score arrays into one 16 KB buffer:
// layout qh[0,2048) | ql[2048,4096) | kh[4096,6144) | kl[6144,8192).
// 4 g2l16 per thread (the vmcnt accounting in scores_mfma depends on this).
__device__ __forceinline__ void stageS16(const f16* __restrict__ qhB,
                                         const f16* __restrict__ qlB,
                                         const f16* __restrict__ khB,
                                         const f16* __restrict__ klB,
                                         int d0, f16* buf, int t) {
  int row = t >> 1, jp = t & 1;
  int jl = jp ^ ((row >> 2) & 1);
  size_t go = (size_t)row * DM + d0 + jl * 8;
  int lo = t * 8;
  g2l16(qhB + go, buf + lo);
  g2l16(qlB + go, buf + 2048 + lo);
  g2l16(khB + go, buf + 4096 + lo);
  g2l16(klB + go, buf + 6144 + lo);
}

// ---- 32x32x16 MFMA. A/B per-lane: [m = lane&31][k = (lane>>5)*8 + j].
// C/D per-lane: col = lane&31, row = (reg&3) + 8*(reg>>2) + 4*(lane>>5).
__device__ __forceinline__ void chunk3_32(const f16* Ah, const f16* Al,
                                          const f16* Bh, const f16* Bl,
                                          fx16 acc[2][2], int wm, int wn, int lane) {
  const int r31 = lane & 31;
  const int kq = (lane >> 5) * 8;
#pragma unroll
  for (int k0 = 0; k0 < 32; k0 += 16) {
    f16x8 ah[2], al[2];
#pragma unroll
    for (int it = 0; it < 2; ++it) {
      int row = wm * 64 + it * 32 + r31;
      ah[it] = frag32(Ah, row, k0 + kq);
      al[it] = frag32(Al, row, k0 + kq);
    }
#pragma unroll
    for (int jt = 0; jt < 2; ++jt) {
      int col = wn * 64 + jt * 32 + r31;
      f16x8 bh = frag32(Bh, col, k0 + kq);
      f16x8 bl = frag32(Bl, col, k0 + kq);
#pragma unroll
      for (int it = 0; it < 2; ++it) {
        acc[it][jt] = __builtin_amdgcn_mfma_f32_32x32x16_f16(ah[it], bh, acc[it][jt], 0, 0, 0);
        acc[it][jt] = __builtin_amdgcn_mfma_f32_32x32x16_f16(ah[it], bl, acc[it][jt], 0, 0, 0);
        acc[it][jt] = __builtin_amdgcn_mfma_f32_32x32x16_f16(al[it], bh, acc[it][jt], 0, 0, 0);
      }
    }
  }
}

// same per-acc k/pass order as chunk3_32, one K=16 step from a stageS16 buffer.
__device__ __forceinline__ void chunk3_16w(const f16* buf, fx16 acc[2][2],
                                           int wm, int wn, int lane) {
  const int r31 = lane & 31;
  const int kq = (lane >> 5) * 8;
  f16x8 ah[2], al[2];
#pragma unroll
  for (int it = 0; it < 2; ++it) {
    int row = wm * 64 + it * 32 + r31;
    ah[it] = frag16(buf, row, kq);
    al[it] = frag16(buf + 2048, row, kq);
  }
#pragma unroll
  for (int jt = 0; jt < 2; ++jt) {
    int col = wn * 64 + jt * 32 + r31;
    f16x8 bh = frag16(buf + 4096, col, kq);
    f16x8 bl = frag16(buf + 6144, col, kq);
#pragma unroll
    for (int it = 0; it < 2; ++it) {
      acc[it][jt] = __builtin_amdgcn_mfma_f32_32x32x16_f16(ah[it], bh, acc[it][jt], 0, 0, 0);
      acc[it][jt] = __builtin_amdgcn_mfma_f32_32x32x16_f16(ah[it], bl, acc[it][jt], 0, 0, 0);
      acc[it][jt] = __builtin_amdgcn_mfma_f32_32x32x16_f16(al[it], bh, acc[it][jt], 0, 0, 0);
    }
  }
}

__device__ __forceinline__ void chunk1_64(const f16* A, const f16* B,
                                          fx16 acc[2][2], int wm, int wn, int lane) {
  const int r31 = lane & 31;
  const int kq = (lane >> 5) * 8;
#pragma unroll
  for (int k0 = 0; k0 < 64; k0 += 16) {
    f16x8 a[2];
#pragma unroll
    for (int it = 0; it < 2; ++it)
      a[it] = frag64(A, wm * 64 + it * 32 + r31, k0 + kq);
#pragma unroll
    for (int jt = 0; jt < 2; ++jt) {
      f16x8 b = frag64(B, wn * 64 + jt * 32 + r31, k0 + kq);
#pragma unroll
      for (int it = 0; it < 2; ++it)
        acc[it][jt] = __builtin_amdgcn_mfma_f32_32x32x16_f16(a[it], b, acc[it][jt], 0, 0, 0);
    }
  }
}

// ---------------------------------------------------------------------------
// Convert: x and Wq/Wk/Wv -> scaled split f16 (v*32 = hi + lo).
// ---------------------------------------------------------------------------
__global__ __launch_bounds__(256) void convert_split(
    const float* __restrict__ x, const float* __restrict__ Wq,
    const float* __restrict__ Wk, const float* __restrict__ Wv,
    f16* __restrict__ xh, f16* __restrict__ xl,
    f16* __restrict__ Wh, f16* __restrict__ Wl) {
  int idx = blockIdx.x * 256 + threadIdx.x;   // float4 index, 0..2293759
  const float* src; f16* dh; f16* dl; size_t off;
  if (idx < 2097152) { src = x; off = (size_t)idx; dh = xh; dl = xl; }
  else {
    int rr = idx - 2097152;
    int w = rr >> 16, o = rr & 65535;
    src = (w == 0) ? Wq : (w == 1) ? Wk : Wv;
    off = (size_t)o;
    dh = Wh + (size_t)w * 262144; dl = Wl + (size_t)w * 262144;
  }
  float4 v = ((const float4*)src)[off];
  float vv[4] = {v.x, v.y, v.z, v.w};
  f16x4 hv, lv;
#pragma unroll
  for (int i = 0; i < 4; ++i) {
    float s = vv[i] * 32.0f;
    f16 hi = (f16)s;
    hv[i] = hi;
    lv[i] = (f16)(s - (float)hi);
  }
  *(f16x4*)(dh + off * 4) = hv;
  *(f16x4*)(dl + off * 4) = lv;
}

// ---------------------------------------------------------------------------
// QKV, double-buffered (exact R0): C = x*W^T + b. z=0 -> q split; z=1 -> k
// split (both 3-pass); z=2 -> v single f16 TRANSPOSED (1-pass).
// ---------------------------------------------------------------------------
__global__ __launch_bounds__(256) void qkv_mfma(
    const f16* __restrict__ xh, const f16* __restrict__ xl,
    const f16* __restrict__ Wh, const f16* __restrict__ Wl,
    const float* __restrict__ bq, const float* __restrict__ bk, const float* __restrict__ bv,
    f16* __restrict__ qh, f16* __restrict__ ql,
    f16* __restrict__ kh, f16* __restrict__ kl,
    f16* __restrict__ vt) {
  __shared__ __align__(16) f16 sm[32768];   // 64 KB = 2 x 32 KB buffers
  const int t = threadIdx.x;
  const int i0 = blockIdx.x * 128, j0 = blockIdx.y * 128, z = blockIdx.z;
  const f16* WhZ = Wh + (size_t)z * 262144;
  const f16* WlZ = Wl + (size_t)z * 262144;
  const int lane = t & 63, wave = t >> 6;
  const int wm = wave >> 1, wn = wave & 1;
  const int r31 = lane & 31, half = lane >> 5;
  fx16 acc[2][2] = {};
  const f16* xhB = xh + (size_t)i0 * DM;
  const f16* xlB = xl + (size_t)i0 * DM;
  const f16* WhB = WhZ + (size_t)j0 * DM;
  const f16* WlB = WlZ + (size_t)j0 * DM;
  if (z < 2) {
    // prologue: chunk 0 into buf0
    stage32(xhB, DM, sm, t);
    stage32(xlB, DM, sm + 4096, t);
    stage32(WhB, DM, sm + 8192, t);
    stage32(WlB, DM, sm + 12288, t);
    __syncthreads();
    for (int c = 0; c < 16; ++c) {
      f16* cur = sm + (c & 1) * 16384;
      if (c < 15) {
        f16* nxt = sm + ((c + 1) & 1) * 16384;
        int d0 = (c + 1) * 32;
        stage32(xhB + d0, DM, nxt, t);
        stage32(xlB + d0, DM, nxt + 4096, t);
        stage32(WhB + d0, DM, nxt + 8192, t);
        stage32(WlB + d0, DM, nxt + 12288, t);
      }
      chunk3_32(cur, cur + 4096, cur + 8192, cur + 12288, acc, wm, wn, lane);
      if (c < 15) __syncthreads();
    }
  } else {
    stage64(xhB, DM, sm, t);
    stage64(WhB, DM, sm + 8192, t);
    __syncthreads();
    for (int c = 0; c < 8; ++c) {
      f16* cur = sm + (c & 1) * 16384;
      if (c < 7) {
        f16* nxt = sm + ((c + 1) & 1) * 16384;
        int d0 = (c + 1) * 64;
        stage64(xhB + d0, DM, nxt, t);
        stage64(WhB + d0, DM, nxt + 8192, t);
      }
      chunk1_64(cur, cur + 8192, acc, wm, wn, lane);
      if (c < 7) __syncthreads();
    }
  }
  const float* bias = (z == 0) ? bq : (z == 1) ? bk : bv;
  if (z < 2) {
    f16* oh = z ? kh : qh;  f16* ol = z ? kl : ql;
#pragma unroll
    for (int it = 0; it < 2; ++it)
#pragma unroll
      for (int jt = 0; jt < 2; ++jt) {
        int j = j0 + wn * 64 + jt * 32 + r31;
        float bj = bias[j];
#pragma unroll
        for (int r = 0; r < 16; ++r) {
          int ib = i0 + wm * 64 + it * 32 + (r & 3) + 8 * (r >> 2) + 4 * half;
          float val = acc[it][jt][r] * (1.0f / 1024.0f) + bj;   // exact f32 value
          float s = val * 32.0f;                                 // re-split, scaled
          f16 hi = (f16)s;
          oh[(size_t)ib * DM + j] = hi;
          ol[(size_t)ib * DM + j] = (f16)(s - (float)hi);
        }
      }
  } else {
#pragma unroll
    for (int it = 0; it < 2; ++it)
#pragma unroll
      for (int jt = 0; jt < 2; ++jt) {
        int j = j0 + wn * 64 + jt * 32 + r31;
        float bj = bias[j];
#pragma unroll
        for (int q4 = 0; q4 < 4; ++q4) {
          int ib = i0 + wm * 64 + it * 32 + 8 * q4 + 4 * half;   // 4 consecutive rows
          int bb = ib >> 11, nb = ib & 2047;
          f16x4 hv;
#pragma unroll
          for (int g = 0; g < 4; ++g)
            hv[g] = (f16)(acc[it][jt][q4 * 4 + g] * (1.0f / 1024.0f) + bj);
          *(f16x4*)(vt + ((size_t)(bb * DM + j)) * SEQ + nb) = hv;
        }
      }
  }
}

// ---------------------------------------------------------------------------
// Scores: R0 geometry (4 waves x 64x64, read:MFMA = 0.67) with the drain
// removed. BK=16 chunks in a TRIPLE buffer (48 KB -> 3 blocks/CU), prefetch
// distance 2, raw s_barrier + counted s_waitcnt vmcnt(8) (= 2 chunks x 4
// loads/thread stay in flight across every barrier; tail 8->4->0). Buffer
// reuse is protected by a cheap lgkmcnt(0) barrier (already satisfied by the
// MFMAs having consumed the ds_reads). K-step order, pass order and rounding
// identical to R0 -> bit-identical output (absmax canary 0.0004882812).
// ---------------------------------------------------------------------------
__global__ __launch_bounds__(256) void scores_mfma(
    const f16* __restrict__ qh, const f16* __restrict__ ql,
    const f16* __restrict__ kh, const f16* __restrict__ kl,
    const float* __restrict__ qa, const float* __restrict__ ka,
    const int* __restrict__ adj,
    const float* __restrict__ mc_p, const float* __restrict__ thr_p,
    f16* __restrict__ S16) {
  __shared__ __align__(16) f16 sm[24576];   // 48 KB = 3 x 16 KB chunk buffers
  const int t = threadIdx.x;
  const int n0 = blockIdx.x * 128, m0 = blockIdx.y * 128, b = blockIdx.z;
  const int lane = t & 63, wave = t >> 6;
  const int wm = wave >> 1, wn = wave & 1;
  const int r31 = lane & 31, half = lane >> 5;
  const int kq = half * 8;

  const f16* qhB = qh + ((size_t)b * SEQ + n0) * DM;
  const f16* qlB = ql + ((size_t)b * SEQ + n0) * DM;
  const f16* khB = kh + ((size_t)b * SEQ + m0) * DM;
  const f16* klB = kl + ((size_t)b * SEQ + m0) * DM;
  f16* const B0 = sm;
  f16* const B1 = sm + 8192;
  f16* const B2 = sm + 16384;

  // ---- chunk 0 -> buf0 (async; overlaps the aux phase) ----
  stageS16(qhB, qlB, khB, klB, 0, B0, t);

  // ---- aux tiles [128][64] f16 x2 into buf1+buf2 via plain stores ----
  f16* QAl = B1;
  f16* KAl = B2;
  const float* QAb = qa + ((size_t)b * SEQ + n0) * DAUX;
  const float* KAb = ka + ((size_t)b * SEQ + m0) * DAUX;
#pragma unroll
  for (int p = 0; p < 4; ++p) {
    int L8 = p * 256 + t;
    int row = L8 >> 3, jb = L8 & 7;
    int c8 = jb * 8;
    int jp = jb ^ (row & 7);
    float4 u0 = *(const float4*)(QAb + (size_t)row * DAUX + c8);
    float4 u1 = *(const float4*)(QAb + (size_t)row * DAUX + c8 + 4);
    f16x8 hq = {(f16)u0.x,(f16)u0.y,(f16)u0.z,(f16)u0.w,(f16)u1.x,(f16)u1.y,(f16)u1.z,(f16)u1.w};
    *(f16x8*)(QAl + row * 64 + jp * 8) = hq;
    float4 w0 = *(const float4*)(KAb + (size_t)row * DAUX + c8);
    float4 w1 = *(const float4*)(KAb + (size_t)row * DAUX + c8 + 4);
    f16x8 hk = {(f16)w0.x,(f16)w0.y,(f16)w0.z,(f16)w0.w,(f16)w1.x,(f16)w1.y,(f16)w1.z,(f16)w1.w};
    *(f16x8*)(KAl + row * 64 + jp * 8) = hk;
  }
  WAITL0; BAR;              // aux writes visible; chunk-0 g2l NOT drained

  // ---- aux MFMA phase (reads buf1/2; same k-order and rounding as R0) ----
  f16x2 sax2[2][2][8];
  {
    fx16 aacc[2][2] = {};
#pragma unroll
    for (int k0 = 0; k0 < 64; k0 += 16) {
      f16x8 qaf[2];
#pragma unroll
      for (int it = 0; it < 2; ++it)
        qaf[it] = frag64(QAl, wm * 64 + it * 32 + r31, k0 + kq);
#pragma unroll
      for (int jt = 0; jt < 2; ++jt) {
        f16x8 kaf = frag64(KAl, wn * 64 + jt * 32 + r31, k0 + kq);
#pragma unroll
        for (int it = 0; it < 2; ++it)
          aacc[it][jt] = __builtin_amdgcn_mfma_f32_32x32x16_f16(qaf[it], kaf, aacc[it][jt], 0, 0, 0);
      }
    }
#pragma unroll
    for (int it = 0; it < 2; ++it)
#pragma unroll
      for (int jt = 0; jt < 2; ++jt)
#pragma unroll
        for (int r = 0; r < 16; ++r)
          sax2[it][jt][r >> 1][r & 1] = (f16)aacc[it][jt][r];
  }
  WAITL0; BAR;              // all aux reads consumed; buf1/2 free

  // ---- prime the pipeline: chunks 1,2 in flight ----
  stageS16(qhB, qlB, khB, klB, 16, B1, t);
  stageS16(qhB, qlB, khB, klB, 32, B2, t);

  // ---- main loop: 32 BK=16 chunks, counted vmcnt, no drains ----
  fx16 acc[2][2] = {};
  for (int c = 0; c < 27; c += 3) {
    WAITV8; BAR;
    chunk3_16w(B0, acc, wm, wn, lane);
    WAITL0; BAR;
    stageS16(qhB, qlB, khB, klB, (c + 3) * 16, B0, t);

    WAITV8; BAR;
    chunk3_16w(B1, acc, wm, wn, lane);
    WAITL0; BAR;
    stageS16(qhB, qlB, khB, klB, (c + 4) * 16, B1, t);

    WAITV8; BAR;
    chunk3_16w(B2, acc, wm, wn, lane);
    WAITL0; BAR;
    stageS16(qhB, qlB, khB, klB, (c + 5) * 16, B2, t);
  }
  // chunks 27, 28 (issue 30, 31)
  WAITV8; BAR; chunk3_16w(B0, acc, wm, wn, lane); WAITL0; BAR;
  stageS16(qhB, qlB, khB, klB, 480, B0, t);
  WAITV8; BAR; chunk3_16w(B1, acc, wm, wn, lane); WAITL0; BAR;
  stageS16(qhB, qlB, khB, klB, 496, B1, t);
  // chunks 29, 30, 31 — tail drain 8 -> 4 -> 0
  WAITV8; BAR; chunk3_16w(B2, acc, wm, wn, lane); WAITL0; BAR;
  WAITV4; BAR; chunk3_16w(B0, acc, wm, wn, lane); WAITL0; BAR;
  WAITV0; BAR; chunk3_16w(B1, acc, wm, wn, lane);

  // ---- merge + mask + f16 store (identical to R0) ----
  const float mc = *mc_p, thr = *thr_p;
  const float invC = 1.0f / (1024.0f * 22.62741699796952f);  // /(32*32)/sqrt(512)
#pragma unroll
  for (int it = 0; it < 2; ++it)
#pragma unroll
    for (int jt = 0; jt < 2; ++jt) {
      int col = m0 + wn * 64 + jt * 32 + r31;
#pragma unroll
      for (int r = 0; r < 16; ++r) {
        int row = n0 + wm * 64 + it * 32 + (r & 3) + 8 * (r >> 2) + 4 * half;
        size_t rbase = ((size_t)b * SEQ + row) * SEQ;
        float s = acc[it][jt][r] * invC;
        float sa = (float)sax2[it][jt][r >> 1][r & 1] * 0.125f;
        if (sa != 0.0f && s > thr) s = (1.0f - mc) * s + mc * sa;
        if (adj[rbase + col] == 0) s = -65504.0f;   // f16 min -> exp()==0
        S16[rbase + col] = (f16)s;
      }
    }
}

// ---------------------------------------------------------------------------
// Softmax: one WAVE per row (4 rows/block, no barriers). In-place S16 row ->
// P16 = 1024*exp(s-max); rowsum = sum of the ROUNDED P16 (exact normalization).
// ---------------------------------------------------------------------------
__global__ __launch_bounds__(256) void softmax_p(
    f16* __restrict__ S16, float* __restrict__ rowsum) {
  const int wv = threadIdx.x >> 6, ln = threadIdx.x & 63;
  const size_t row = (size_t)blockIdx.x * 4 + wv;
  f16* Sr = S16 + row * SEQ;
  f16x8 v[4];
  float vals[32];
#pragma unroll
  for (int j = 0; j < 4; ++j) {
    v[j] = *(const f16x8*)(Sr + j * 512 + ln * 8);
#pragma unroll
    for (int i = 0; i < 8; ++i) vals[j * 8 + i] = (float)v[j][i];
  }
  float m = vals[0];
#pragma unroll
  for (int i = 1; i < 32; ++i) m = fmaxf(m, vals[i]);
#pragma unroll
  for (int off = 1; off < 64; off <<= 1) m = fmaxf(m, __shfl_xor(m, off, 64));
  float z = 0.f;
  f16x8 p16[4];
#pragma unroll
  for (int j = 0; j < 4; ++j)
#pragma unroll
    for (int i = 0; i < 8; ++i) {
      f16 p = (f16)(__expf(vals[j * 8 + i] - m) * 1024.0f);
      p16[j][i] = p;
      z += (float)p;
    }
#pragma unroll
  for (int off = 1; off < 64; off <<= 1) z += __shfl_xor(z, off, 64);
  if (ln == 0) rowsum[row] = z;
#pragma unroll
  for (int j = 0; j < 4; ++j)
    *(f16x8*)(Sr + j * 512 + ln * 8) = p16[j];
}

// ---------------------------------------------------------------------------
// PV, double-buffered (exact R0): O[n][d] = (sum_m P16[n][m]*vt[d][m])/rowsum[n].
// ---------------------------------------------------------------------------
__global__ __launch_bounds__(256) void pv_mfma(
    const f16* __restrict__ P16, const f16* __restrict__ vt,
    const float* __restrict__ rowsum, float* __restrict__ O) {
  __shared__ __align__(16) f16 sm[32768];   // 64 KB = 2 x (Ps 16KB + Vs 16KB)
  const int t = threadIdx.x;
  const int n0 = blockIdx.x * 128, d0 = blockIdx.y * 128, b = blockIdx.z;
  const int lane = t & 63, wave = t >> 6;
  const int wm = wave >> 1, wn = wave & 1;
  const int r31 = lane & 31, half = lane >> 5;
  fx16 acc[2][2] = {};
  const f16* Pb = P16 + ((size_t)b * SEQ + n0) * SEQ;
  const f16* Vb = vt + ((size_t)b * DM + d0) * SEQ;
  stage64(Pb, SEQ, sm, t);
  stage64(Vb, SEQ, sm + 8192, t);
  __syncthreads();
  for (int c = 0; c < 32; ++c) {
    f16* cur = sm + (c & 1) * 16384;
    if (c < 31) {
      f16* nxt = sm + ((c + 1) & 1) * 16384;
      int m0 = (c + 1) * 64;
      stage64(Pb + m0, SEQ, nxt, t);
      stage64(Vb + m0, SEQ, nxt + 8192, t);
    }
    chunk1_64(cur, cur + 8192, acc, wm, wn, lane);
    if (c < 31) __syncthreads();
  }
#pragma unroll
  for (int it = 0; it < 2; ++it)
#pragma unroll
    for (int jt = 0; jt < 2; ++jt) {
      int d = d0 + wn * 64 + jt * 32 + r31;
#pragma unroll
      for (int r = 0; r < 16; ++r) {
        int n = n0 + wm * 64 + it * 32 + (r & 3) + 8 * (r >> 2) + 4 * half;
        float inv = 1.0f / rowsum[(size_t)b * SEQ + n];
        O[((size_t)b * SEQ + n) * DM + d] = acc[it][jt][r] * inv;
      }
    }
}

// ---------------------------------------------------------------------------
extern "C" void kernel_launch(void* const* d_in, const int* in_sizes, int n_in,
                              void* d_out, int out_size, void* d_ws, size_t ws_size,
                              hipStream_t stream) {
  const float* x   = (const float*)d_in[0];
  const float* qa  = (const float*)d_in[1];
  const float* ka  = (const float*)d_in[2];
  const int*   adj = (const int*)d_in[3];
  const float* mc  = (const float*)d_in[4];
  const float* Wq  = (const float*)d_in[5];
  const float* bq  = (const float*)d_in[6];
  const float* Wk  = (const float*)d_in[7];
  const float* bk  = (const float*)d_in[8];
  const float* Wv  = (const float*)d_in[9];
  const float* bv  = (const float*)d_in[10];
  const float* thr = (const float*)d_in[11];
  float* out = (float*)d_out;

  // ws layout (f16 elems): qh|ql|kh|kl|vt (8.39M each) | S16 (33.55M) | rowsum
  // convert outputs xh/xl/Wh/Wl alias the S16 region (dead before S16 written).
  f16* qh  = (f16*)d_ws;
  f16* ql  = qh + 8388608;
  f16* kh  = ql + 8388608;
  f16* kl  = kh + 8388608;
  f16* vt  = kl + 8388608;
  f16* S16 = vt + 8388608;
  float* rowsum = (float*)(S16 + 33554432);
  f16* xh = S16;                 // alias
  f16* xl = xh + 8388608;
  f16* Wh = xl + 8388608;        // [3][512*512]
  f16* Wl = Wh + 786432;

  convert_split<<<8960, 256, 0, stream>>>(x, Wq, Wk, Wv, xh, xl, Wh, Wl);
  qkv_mfma<<<dim3(128, 4, 3), 256, 0, stream>>>(xh, xl, Wh, Wl, bq, bk, bv,
                                                qh, ql, kh, kl, vt);
  scores_mfma<<<dim3(16, 16, 8), 256, 0, stream>>>(qh, ql, kh, kl, qa, ka, adj,
                                                   mc, thr, S16);
  softmax_p<<<4096, 256, 0, stream>>>(S16, rowsum);
  pv_mfma<<<dim3(16, 4, 8), 256, 0, stream>>>(S16, vt, rowsum, out);
}

// Round 6
// 558.313 us; speedup vs baseline: 1.0064x; 1.0064x over previous
//
#include <hip/hip_runtime.h>
#include <cstdint>

#define SEQ    2048
#define DM     512
#define DAUX   64

typedef _Float16 f16;
typedef __attribute__((ext_vector_type(2))) _Float16 f16x2;
typedef __attribute__((ext_vector_type(4))) _Float16 f16x4;
typedef __attribute__((ext_vector_type(8))) _Float16 f16x8;
typedef __attribute__((ext_vector_type(4))) float fx4;
typedef __attribute__((ext_vector_type(16))) float fx16;

// async global->LDS, 16B per lane. LDS dest must be wave-uniform base + lane*16.
__device__ __forceinline__ void g2l16(const void* g, void* l) {
  __builtin_amdgcn_global_load_lds(
      (__attribute__((address_space(1))) void*)const_cast<void*>(g),
      (__attribute__((address_space(3))) void*)l, 16, 0, 0);
}

// counted-vmcnt primitives (T4). vmcnt retires in issue order (m135): waiting
// to <=4 outstanding retires exactly the oldest group of 4 g2l16 loads.
// sched_barrier(0) after each asm/barrier pins VMEM/DS issue order (rule #18).
#define WAITV4 { asm volatile("s_waitcnt vmcnt(4)" ::: "memory"); __builtin_amdgcn_sched_barrier(0); }
#define WAITV0 { asm volatile("s_waitcnt vmcnt(0)" ::: "memory"); __builtin_amdgcn_sched_barrier(0); }
#define WAITL0 { asm volatile("s_waitcnt lgkmcnt(0)" ::: "memory"); __builtin_amdgcn_sched_barrier(0); }
#define BAR { __builtin_amdgcn_s_barrier(); __builtin_amdgcn_sched_barrier(0); }

// ---- BK=32 tile [128][32], XOR swizzle on 8-elem blocks (jp ^ (row>>1)&3).
__device__ __forceinline__ void stage32(const f16* __restrict__ g0, int stride,
                                        f16* lds, int t) {
#pragma unroll
  for (int p = 0; p < 2; ++p) {
    int L = p * 256 + t;          // 0..511
    int row = L >> 2;             // 0..127
    int jp = L & 3;
    int jl = jp ^ ((row >> 1) & 3);
    g2l16(g0 + (size_t)row * stride + jl * 8, lds + L * 8);
  }
}
__device__ __forceinline__ f16x8 frag32(const f16* lds, int row, int kq) {
  int jp = (kq >> 3) ^ ((row >> 1) & 3);
  return *(const f16x8*)(lds + row * 32 + jp * 8);
}

// ---- BK=64 tile [128][64], swizzle jp ^ (row&7) (measured conflict-free).
__device__ __forceinline__ void stage64(const f16* __restrict__ g0, int stride,
                                        f16* lds, int t) {
#pragma unroll
  for (int p = 0; p < 4; ++p) {
    int L = p * 256 + t;          // 0..1023
    int row = L >> 3;
    int jp = L & 7;
    int jl = jp ^ (row & 7);
    g2l16(g0 + (size_t)row * stride + jl * 8, lds + L * 8);
  }
}
__device__ __forceinline__ f16x8 frag64(const f16* lds, int row, int kq) {
  int jp = (kq >> 3) ^ (row & 7);
  return *(const f16x8*)(lds + row * 64 + jp * 8);
}

// ---- BK=16 group [128][16] x 4 arrays, 16 KB total (VERIFIED layout, R4).
// Array a at buf + a*2048; XOR swizzle jl = jp ^ ((row>>2)&1).
__device__ __forceinline__ f16x8 frag16(const f16* lds, int row, int kq) {
  int jp = (kq >> 3) ^ ((row >> 2) & 1);
  return *(const f16x8*)(lds + row * 16 + jp * 8);
}
// 4 g2l16 per thread (one per array) — the vmcnt(4) accounting depends on this.
__device__ __forceinline__ void stageS16(const f16* __restrict__ qhB,
                                         const f16* __restrict__ qlB,
                                         const f16* __restrict__ khB,
                                         const f16* __restrict__ klB,
                                         int d0, f16* buf, int t) {
  int row = t >> 1, jp = t & 1;
  int jl = jp ^ ((row >> 2) & 1);
  size_t go = (size_t)row * DM + d0 + jl * 8;
  int lo = t * 8;
  g2l16(qhB + go, buf + lo);
  g2l16(qlB + go, buf + 2048 + lo);
  g2l16(khB + go, buf + 4096 + lo);
  g2l16(klB + go, buf + 6144 + lo);
}

// ---- 32x32x16 MFMA. A/B per-lane: [m = lane&31][k = (lane>>5)*8 + j].
// C/D per-lane: col = lane&31, row = (reg&3) + 8*(reg>>2) + 4*(lane>>5).
__device__ __forceinline__ void chunk3_32(const f16* Ah, const f16* Al,
                                          const f16* Bh, const f16* Bl,
                                          fx16 acc[2][2], int wm, int wn, int lane) {
  const int r31 = lane & 31;
  const int kq = (lane >> 5) * 8;
#pragma unroll
  for (int k0 = 0; k0 < 32; k0 += 16) {
    f16x8 ah[2], al[2];
#pragma unroll
    for (int it = 0; it < 2; ++it) {
      int row = wm * 64 + it * 32 + r31;
      ah[it] = frag32(Ah, row, k0 + kq);
      al[it] = frag32(Al, row, k0 + kq);
    }
#pragma unroll
    for (int jt = 0; jt < 2; ++jt) {
      int col = wn * 64 + jt * 32 + r31;
      f16x8 bh = frag32(Bh, col, k0 + kq);
      f16x8 bl = frag32(Bl, col, k0 + kq);
#pragma unroll
      for (int it = 0; it < 2; ++it) {
        acc[it][jt] = __builtin_amdgcn_mfma_f32_32x32x16_f16(ah[it], bh, acc[it][jt], 0, 0, 0);
        acc[it][jt] = __builtin_amdgcn_mfma_f32_32x32x16_f16(ah[it], bl, acc[it][jt], 0, 0, 0);
        acc[it][jt] = __builtin_amdgcn_mfma_f32_32x32x16_f16(al[it], bh, acc[it][jt], 0, 0, 0);
      }
    }
  }
}

// One K=16 step from a stageS16 group; same per-acc k/pass order as chunk3_32
// (VERIFIED in R4 - bit-identical to R0's accumulation).
__device__ __forceinline__ void chunk3_16w(const f16* buf, fx16 acc[2][2],
                                           int wm, int wn, int lane) {
  const int r31 = lane & 31;
  const int kq = (lane >> 5) * 8;
  f16x8 ah[2], al[2];
#pragma unroll
  for (int it = 0; it < 2; ++it) {
    int row = wm * 64 + it * 32 + r31;
    ah[it] = frag16(buf, row, kq);
    al[it] = frag16(buf + 2048, row, kq);
  }
#pragma unroll
  for (int jt = 0; jt < 2; ++jt) {
    int col = wn * 64 + jt * 32 + r31;
    f16x8 bh = frag16(buf + 4096, col, kq);
    f16x8 bl = frag16(buf + 6144, col, kq);
#pragma unroll
    for (int it = 0; it < 2; ++it) {
      acc[it][jt] = __builtin_amdgcn_mfma_f32_32x32x16_f16(ah[it], bh, acc[it][jt], 0, 0, 0);
      acc[it][jt] = __builtin_amdgcn_mfma_f32_32x32x16_f16(ah[it], bl, acc[it][jt], 0, 0, 0);
      acc[it][jt] = __builtin_amdgcn_mfma_f32_32x32x16_f16(al[it], bh, acc[it][jt], 0, 0, 0);
    }
  }
}

__device__ __forceinline__ void chunk1_64(const f16* A, const f16* B,
                                          fx16 acc[2][2], int wm, int wn, int lane) {
  const int r31 = lane & 31;
  const int kq = (lane >> 5) * 8;
#pragma unroll
  for (int k0 = 0; k0 < 64; k0 += 16) {
    f16x8 a[2];
#pragma unroll
    for (int it = 0; it < 2; ++it)
      a[it] = frag64(A, wm * 64 + it * 32 + r31, k0 + kq);
#pragma unroll
    for (int jt = 0; jt < 2; ++jt) {
      f16x8 b = frag64(B, wn * 64 + jt * 32 + r31, k0 + kq);
#pragma unroll
      for (int it = 0; it < 2; ++it)
        acc[it][jt] = __builtin_amdgcn_mfma_f32_32x32x16_f16(a[it], b, acc[it][jt], 0, 0, 0);
    }
  }
}

// ---------------------------------------------------------------------------
// Convert: x and Wq/Wk/Wv -> scaled split f16 (v*32 = hi + lo).
// ---------------------------------------------------------------------------
__global__ __launch_bounds__(256) void convert_split(
    const float* __restrict__ x, const float* __restrict__ Wq,
    const float* __restrict__ Wk, const float* __restrict__ Wv,
    f16* __restrict__ xh, f16* __restrict__ xl,
    f16* __restrict__ Wh, f16* __restrict__ Wl) {
  int idx = blockIdx.x * 256 + threadIdx.x;   // float4 index, 0..2293759
  const float* src; f16* dh; f16* dl; size_t off;
  if (idx < 2097152) { src = x; off = (size_t)idx; dh = xh; dl = xl; }
  else {
    int rr = idx - 2097152;
    int w = rr >> 16, o = rr & 65535;
    src = (w == 0) ? Wq : (w == 1) ? Wk : Wv;
    off = (size_t)o;
    dh = Wh + (size_t)w * 262144; dl = Wl + (size_t)w * 262144;
  }
  float4 v = ((const float4*)src)[off];
  float vv[4] = {v.x, v.y, v.z, v.w};
  f16x4 hv, lv;
#pragma unroll
  for (int i = 0; i < 4; ++i) {
    float s = vv[i] * 32.0f;
    f16 hi = (f16)s;
    hv[i] = hi;
    lv[i] = (f16)(s - (float)hi);
  }
  *(f16x4*)(dh + off * 4) = hv;
  *(f16x4*)(dl + off * 4) = lv;
}

// ---------------------------------------------------------------------------
// QKV, double-buffered (exact R0): C = x*W^T + b. z=0 -> q split; z=1 -> k
// split (both 3-pass); z=2 -> v single f16 TRANSPOSED (1-pass).
// ---------------------------------------------------------------------------
__global__ __launch_bounds__(256) void qkv_mfma(
    const f16* __restrict__ xh, const f16* __restrict__ xl,
    const f16* __restrict__ Wh, const f16* __restrict__ Wl,
    const float* __restrict__ bq, const float* __restrict__ bk, const float* __restrict__ bv,
    f16* __restrict__ qh, f16* __restrict__ ql,
    f16* __restrict__ kh, f16* __restrict__ kl,
    f16* __restrict__ vt) {
  __shared__ __align__(16) f16 sm[32768];   // 64 KB = 2 x 32 KB buffers
  const int t = threadIdx.x;
  const int i0 = blockIdx.x * 128, j0 = blockIdx.y * 128, z = blockIdx.z;
  const f16* WhZ = Wh + (size_t)z * 262144;
  const f16* WlZ = Wl + (size_t)z * 262144;
  const int lane = t & 63, wave = t >> 6;
  const int wm = wave >> 1, wn = wave & 1;
  const int r31 = lane & 31, half = lane >> 5;
  fx16 acc[2][2] = {};
  const f16* xhB = xh + (size_t)i0 * DM;
  const f16* xlB = xl + (size_t)i0 * DM;
  const f16* WhB = WhZ + (size_t)j0 * DM;
  const f16* WlB = WlZ + (size_t)j0 * DM;
  if (z < 2) {
    // prologue: chunk 0 into buf0
    stage32(xhB, DM, sm, t);
    stage32(xlB, DM, sm + 4096, t);
    stage32(WhB, DM, sm + 8192, t);
    stage32(WlB, DM, sm + 12288, t);
    __syncthreads();
    for (int c = 0; c < 16; ++c) {
      f16* cur = sm + (c & 1) * 16384;
      if (c < 15) {
        f16* nxt = sm + ((c + 1) & 1) * 16384;
        int d0 = (c + 1) * 32;
        stage32(xhB + d0, DM, nxt, t);
        stage32(xlB + d0, DM, nxt + 4096, t);
        stage32(WhB + d0, DM, nxt + 8192, t);
        stage32(WlB + d0, DM, nxt + 12288, t);
      }
      chunk3_32(cur, cur + 4096, cur + 8192, cur + 12288, acc, wm, wn, lane);
      if (c < 15) __syncthreads();
    }
  } else {
    stage64(xhB, DM, sm, t);
    stage64(WhB, DM, sm + 8192, t);
    __syncthreads();
    for (int c = 0; c < 8; ++c) {
      f16* cur = sm + (c & 1) * 16384;
      if (c < 7) {
        f16* nxt = sm + ((c + 1) & 1) * 16384;
        int d0 = (c + 1) * 64;
        stage64(xhB + d0, DM, nxt, t);
        stage64(WhB + d0, DM, nxt + 8192, t);
      }
      chunk1_64(cur, cur + 8192, acc, wm, wn, lane);
      if (c < 7) __syncthreads();
    }
  }
  const float* bias = (z == 0) ? bq : (z == 1) ? bk : bv;
  if (z < 2) {
    f16* oh = z ? kh : qh;  f16* ol = z ? kl : ql;
#pragma unroll
    for (int it = 0; it < 2; ++it)
#pragma unroll
      for (int jt = 0; jt < 2; ++jt) {
        int j = j0 + wn * 64 + jt * 32 + r31;
        float bj = bias[j];
#pragma unroll
        for (int r = 0; r < 16; ++r) {
          int ib = i0 + wm * 64 + it * 32 + (r & 3) + 8 * (r >> 2) + 4 * half;
          float val = acc[it][jt][r] * (1.0f / 1024.0f) + bj;   // exact f32 value
          float s = val * 32.0f;                                 // re-split, scaled
          f16 hi = (f16)s;
          oh[(size_t)ib * DM + j] = hi;
          ol[(size_t)ib * DM + j] = (f16)(s - (float)hi);
        }
      }
  } else {
#pragma unroll
    for (int it = 0; it < 2; ++it)
#pragma unroll
      for (int jt = 0; jt < 2; ++jt) {
        int j = j0 + wn * 64 + jt * 32 + r31;
        float bj = bias[j];
#pragma unroll
        for (int q4 = 0; q4 < 4; ++q4) {
          int ib = i0 + wm * 64 + it * 32 + 8 * q4 + 4 * half;   // 4 consecutive rows
          int bb = ib >> 11, nb = ib & 2047;
          f16x4 hv;
#pragma unroll
          for (int g = 0; g < 4; ++g)
            hv[g] = (f16)(acc[it][jt][q4 * 4 + g] * (1.0f / 1024.0f) + bj);
          *(f16x4*)(vt + ((size_t)(bb * DM + j)) * SEQ + nb) = hv;
        }
      }
  }
}

// ---------------------------------------------------------------------------
// Scores: R0 geometry (4 waves x 64x64), BK=16 groups in a TRIPLE buffer
// (3 x 16 KB = 48 KB), ONE barrier per chunk (32 total), counted vmcnt:
//   iter c: WAITV4; BAR; stage(c+2 -> buf[(c+2)%3]); compute(buf[c%3]).
// WAITV4 retires only chunk c's 4 loads (issued 2 chunks ago, in-order
// retirement); chunk c+1's 4 stay in flight across the barrier. Overwrite
// safety: buf[(c+2)%3]'s last reader is compute(c-1), whose ds_reads are
// consumed before that wave reaches BAR(c); every stage-write is issued
// after BAR(c). Aux phase identical to R0 (uses G1/G2 before the loop).
// K-step order, pass order, rounding identical to R0 -> bit-identical output.
// ---------------------------------------------------------------------------
__global__ __launch_bounds__(256) void scores_mfma(
    const f16* __restrict__ qh, const f16* __restrict__ ql,
    const f16* __restrict__ kh, const f16* __restrict__ kl,
    const float* __restrict__ qa, const float* __restrict__ ka,
    const int* __restrict__ adj,
    const float* __restrict__ mc_p, const float* __restrict__ thr_p,
    f16* __restrict__ S16) {
  __shared__ __align__(16) f16 sm[24576];   // 48 KB = 3 x 16 KB BK=16 groups
  const int t = threadIdx.x;
  const int n0 = blockIdx.x * 128, m0 = blockIdx.y * 128, b = blockIdx.z;
  const int lane = t & 63, wave = t >> 6;
  const int wm = wave >> 1, wn = wave & 1;
  const int r31 = lane & 31, half = lane >> 5;
  const int kq = half * 8;

  const f16* qhB = qh + ((size_t)b * SEQ + n0) * DM;
  const f16* qlB = ql + ((size_t)b * SEQ + n0) * DM;
  const f16* khB = kh + ((size_t)b * SEQ + m0) * DM;
  const f16* klB = kl + ((size_t)b * SEQ + m0) * DM;
  f16* const G0 = sm;
  f16* const G1 = sm + 8192;
  f16* const G2 = sm + 16384;

  // ---- chunk 0 -> G0 (async; overlaps the whole aux phase) ----
  stageS16(qhB, qlB, khB, klB, 0, G0, t);

  // ---- aux tiles [128][64] f16 x2 into G1+G2 via plain stores (= R0) ----
  f16* QAl = G1;
  f16* KAl = G2;
  const float* QAb = qa + ((size_t)b * SEQ + n0) * DAUX;
  const float* KAb = ka + ((size_t)b * SEQ + m0) * DAUX;
#pragma unroll
  for (int p = 0; p < 4; ++p) {
    int L8 = p * 256 + t;
    int row = L8 >> 3, jb = L8 & 7;
    int c8 = jb * 8;
    int jp = jb ^ (row & 7);
    float4 u0 = *(const float4*)(QAb + (size_t)row * DAUX + c8);
    float4 u1 = *(const float4*)(QAb + (size_t)row * DAUX + c8 + 4);
    f16x8 hq = {(f16)u0.x,(f16)u0.y,(f16)u0.z,(f16)u0.w,(f16)u1.x,(f16)u1.y,(f16)u1.z,(f16)u1.w};
    *(f16x8*)(QAl + row * 64 + jp * 8) = hq;
    float4 w0 = *(const float4*)(KAb + (size_t)row * DAUX + c8);
    float4 w1 = *(const float4*)(KAb + (size_t)row * DAUX + c8 + 4);
    f16x8 hk = {(f16)w0.x,(f16)w0.y,(f16)w0.z,(f16)w0.w,(f16)w1.x,(f16)w1.y,(f16)w1.z,(f16)w1.w};
    *(f16x8*)(KAl + row * 64 + jp * 8) = hk;
  }
  WAITL0; BAR;              // aux LDS writes visible; chunk-0 g2l NOT drained

  // ---- aux MFMA phase (reads G1/G2; same k-order and rounding as R0) ----
  f16x2 sax2[2][2][8];
  {
    fx16 aacc[2][2] = {};
#pragma unroll
    for (int k0 = 0; k0 < 64; k0 += 16) {
      f16x8 qaf[2];
#pragma unroll
      for (int it = 0; it < 2; ++it)
        qaf[it] = frag64(QAl, wm * 64 + it * 32 + r31, k0 + kq);
#pragma unroll
      for (int jt = 0; jt < 2; ++jt) {
        f16x8 kaf = frag64(KAl, wn * 64 + jt * 32 + r31, k0 + kq);
#pragma unroll
        for (int it = 0; it < 2; ++it)
          aacc[it][jt] = __builtin_amdgcn_mfma_f32_32x32x16_f16(qaf[it], kaf, aacc[it][jt], 0, 0, 0);
      }
    }
#pragma unroll
    for (int it = 0; it < 2; ++it)
#pragma unroll
      for (int jt = 0; jt < 2; ++jt)
#pragma unroll
        for (int r = 0; r < 16; ++r)
          sax2[it][jt][r >> 1][r & 1] = (f16)aacc[it][jt][r];
  }
  BAR;                      // every wave's aux ds_reads consumed; G1/G2 free

  // ---- prime: chunk 1 -> G1 (G1 sealed free by the BAR above) ----
  stageS16(qhB, qlB, khB, klB, 16, G1, t);

  // ---- main loop: 32 BK=16 chunks, one counted barrier each ----
  fx16 acc[2][2] = {};
#pragma unroll 1
  for (int cc = 0; cc < 30; cc += 3) {
    // c = cc: compute G0, stage cc+2 -> G2
    WAITV4; BAR;
    stageS16(qhB, qlB, khB, klB, (cc + 2) * 16, G2, t);
    chunk3_16w(G0, acc, wm, wn, lane);
    // c = cc+1: compute G1, stage cc+3 -> G0
    WAITV4; BAR;
    stageS16(qhB, qlB, khB, klB, (cc + 3) * 16, G0, t);
    chunk3_16w(G1, acc, wm, wn, lane);
    // c = cc+2: compute G2, stage cc+4 -> G1
    WAITV4; BAR;
    stageS16(qhB, qlB, khB, klB, (cc + 4) * 16, G1, t);
    chunk3_16w(G2, acc, wm, wn, lane);
  }
  // c = 30 (chunk 30 in G0): chunk31's 4 loads stay in flight
  WAITV4; BAR;
  chunk3_16w(G0, acc, wm, wn, lane);
  // c = 31 (chunk 31 in G1): final drain
  WAITV0; BAR;
  chunk3_16w(G1, acc, wm, wn, lane);

  // ---- merge + mask + f16 store (identical to R0) ----
  const float mc = *mc_p, thr = *thr_p;
  const float invC = 1.0f / (1024.0f * 22.62741699796952f);  // /(32*32)/sqrt(512)
#pragma unroll
  for (int it = 0; it < 2; ++it)
#pragma unroll
    for (int jt = 0; jt < 2; ++jt) {
      int col = m0 + wn * 64 + jt * 32 + r31;
#pragma unroll
      for (int r = 0; r < 16; ++r) {
        int row = n0 + wm * 64 + it * 32 + (r & 3) + 8 * (r >> 2) + 4 * half;
        size_t rbase = ((size_t)b * SEQ + row) * SEQ;
        float s = acc[it][jt][r] * invC;
        float sa = (float)sax2[it][jt][r >> 1][r & 1] * 0.125f;
        if (sa != 0.0f && s > thr) s = (1.0f - mc) * s + mc * sa;
        if (adj[rbase + col] == 0) s = -65504.0f;   // f16 min -> exp()==0
        S16[rbase + col] = (f16)s;
      }
    }
}

// ---------------------------------------------------------------------------
// Softmax: one WAVE per row (4 rows/block, no barriers). In-place S16 row ->
// P16 = 1024*exp(s-max); rowsum = sum of the ROUNDED P16 (exact normalization).
// ---------------------------------------------------------------------------
__global__ __launch_bounds__(256) void softmax_p(
    f16* __restrict__ S16, float* __restrict__ rowsum) {
  const int wv = threadIdx.x >> 6, ln = threadIdx.x & 63;
  const size_t row = (size_t)blockIdx.x * 4 + wv;
  f16* Sr = S16 + row * SEQ;
  f16x8 v[4];
  float vals[32];
#pragma unroll
  for (int j = 0; j < 4; ++j) {
    v[j] = *(const f16x8*)(Sr + j * 512 + ln * 8);
#pragma unroll
    for (int i = 0; i < 8; ++i) vals[j * 8 + i] = (float)v[j][i];
  }
  float m = vals[0];
#pragma unroll
  for (int i = 1; i < 32; ++i) m = fmaxf(m, vals[i]);
#pragma unroll
  for (int off = 1; off < 64; off <<= 1) m = fmaxf(m, __shfl_xor(m, off, 64));
  float z = 0.f;
  f16x8 p16[4];
#pragma unroll
  for (int j = 0; j < 4; ++j)
#pragma unroll
    for (int i = 0; i < 8; ++i) {
      f16 p = (f16)(__expf(vals[j * 8 + i] - m) * 1024.0f);
      p16[j][i] = p;
      z += (float)p;
    }
#pragma unroll
  for (int off = 1; off < 64; off <<= 1) z += __shfl_xor(z, off, 64);
  if (ln == 0) rowsum[row] = z;
#pragma unroll
  for (int j = 0; j < 4; ++j)
    *(f16x8*)(Sr + j * 512 + ln * 8) = p16[j];
}

// ---------------------------------------------------------------------------
// PV, double-buffered (exact R0): O[n][d] = (sum_m P16[n][m]*vt[d][m])/rowsum[n].
// ---------------------------------------------------------------------------
__global__ __launch_bounds__(256) void pv_mfma(
    const f16* __restrict__ P16, const f16* __restrict__ vt,
    const float* __restrict__ rowsum, float* __restrict__ O) {
  __shared__ __align__(16) f16 sm[32768];   // 64 KB = 2 x (Ps 16KB + Vs 16KB)
  const int t = threadIdx.x;
  const int n0 = blockIdx.x * 128, d0 = blockIdx.y * 128, b = blockIdx.z;
  const int lane = t & 63, wave = t >> 6;
  const int wm = wave >> 1, wn = wave & 1;
  const int r31 = lane & 31, half = lane >> 5;
  fx16 acc[2][2] = {};
  const f16* Pb = P16 + ((size_t)b * SEQ + n0) * SEQ;
  const f16* Vb = vt + ((size_t)b * DM + d0) * SEQ;
  stage64(Pb, SEQ, sm, t);
  stage64(Vb, SEQ, sm + 8192, t);
  __syncthreads();
  for (int c = 0; c < 32; ++c) {
    f16* cur = sm + (c & 1) * 16384;
    if (c < 31) {
      f16* nxt = sm + ((c + 1) & 1) * 16384;
      int m0 = (c + 1) * 64;
      stage64(Pb + m0, SEQ, nxt, t);
      stage64(Vb + m0, SEQ, nxt + 8192, t);
    }
    chunk1_64(cur, cur + 8192, acc, wm, wn, lane);
    if (c < 31) __syncthreads();
  }
#pragma unroll
  for (int it = 0; it < 2; ++it)
#pragma unroll
    for (int jt = 0; jt < 2; ++jt) {
      int d = d0 + wn * 64 + jt * 32 + r31;
#pragma unroll
      for (int r = 0; r < 16; ++r) {
        int n = n0 + wm * 64 + it * 32 + (r & 3) + 8 * (r >> 2) + 4 * half;
        float inv = 1.0f / rowsum[(size_t)b * SEQ + n];
        O[((size_t)b * SEQ + n) * DM + d] = acc[it][jt][r] * inv;
      }
    }
}

// ---------------------------------------------------------------------------
extern "C" void kernel_launch(void* const* d_in, const int* in_sizes, int n_in,
                              void* d_out, int out_size, void* d_ws, size_t ws_size,
                              hipStream_t stream) {
  const float* x   = (const float*)d_in[0];
  const float* qa  = (const float*)d_in[1];
  const float* ka  = (const float*)d_in[2];
  const int*   adj = (const int*)d_in[3];
  const float* mc  = (const float*)d_in[4];
  const float* Wq  = (const float*)d_in[5];
  const float* bq  = (const float*)d_in[6];
  const float* Wk  = (const float*)d_in[7];
  const float* bk  = (const float*)d_in[8];
  const float* Wv  = (const float*)d_in[9];
  const float* bv  = (const float*)d_in[10];
  const float* thr = (const float*)d_in[11];
  float* out = (float*)d_out;

  // ws layout (f16 elems): qh|ql|kh|kl|vt (8.39M each) | S16 (33.55M) | rowsum
  // convert outputs xh/xl/Wh/Wl alias the S16 region (dead before S16 written).
  f16* qh  = (f16*)d_ws;
  f16* ql  = qh + 8388608;
  f16* kh  = ql + 8388608;
  f16* kl  = kh + 8388608;
  f16* vt  = kl + 8388608;
  f16* S16 = vt + 8388608;
  float* rowsum = (float*)(S16 + 33554432);
  f16* xh = S16;                 // alias
  f16* xl = xh + 8388608;
  f16* Wh = xl + 8388608;        // [3][512*512]
  f16* Wl = Wh + 786432;

  convert_split<<<8960, 256, 0, stream>>>(x, Wq, Wk, Wv, xh, xl, Wh, Wl);
  qkv_mfma<<<dim3(128, 4, 3), 256, 0, stream>>>(xh, xl, Wh, Wl, bq, bk, bv,
                                                qh, ql, kh, kl, vt);
  scores_mfma<<<dim3(16, 16, 8), 256, 0, stream>>>(qh, ql, kh, kl, qa, ka, adj,
                                                   mc, thr, S16);
  softmax_p<<<4096, 256, 0, stream>>>(S16, rowsum);
  pv_mfma<<<dim3(16, 4, 8), 256, 0, stream>>>(S16, vt, rowsum, out);
}

// Round 7
// 542.612 us; speedup vs baseline: 1.0355x; 1.0289x over previous
//
#include <hip/hip_runtime.h>
#include <cstdint>

#define SEQ    2048
#define DM     512
#define DAUX   64

typedef _Float16 f16;
typedef __attribute__((ext_vector_type(2))) _Float16 f16x2;
typedef __attribute__((ext_vector_type(4))) _Float16 f16x4;
typedef __attribute__((ext_vector_type(8))) _Float16 f16x8;
typedef __attribute__((ext_vector_type(4))) float fx4;
typedef __attribute__((ext_vector_type(16))) float fx16;

// async global->LDS, 16B per lane. LDS dest must be wave-uniform base + lane*16.
__device__ __forceinline__ void g2l16(const void* g, void* l) {
  __builtin_amdgcn_global_load_lds(
      (__attribute__((address_space(1))) void*)const_cast<void*>(g),
      (__attribute__((address_space(3))) void*)l, 16, 0, 0);
}

// ---- BK=32 tile [128][32], XOR swizzle on 8-elem blocks (jp ^ (row>>1)&3).
__device__ __forceinline__ void stage32(const f16* __restrict__ g0, int stride,
                                        f16* lds, int t) {
#pragma unroll
  for (int p = 0; p < 2; ++p) {
    int L = p * 256 + t;          // 0..511
    int row = L >> 2;             // 0..127
    int jp = L & 3;
    int jl = jp ^ ((row >> 1) & 3);
    g2l16(g0 + (size_t)row * stride + jl * 8, lds + L * 8);
  }
}
__device__ __forceinline__ f16x8 frag32(const f16* lds, int row, int kq) {
  int jp = (kq >> 3) ^ ((row >> 1) & 3);
  return *(const f16x8*)(lds + row * 32 + jp * 8);
}

// ---- BK=64 tile [128][64], swizzle jp ^ (row&7) (measured conflict-free).
__device__ __forceinline__ void stage64(const f16* __restrict__ g0, int stride,
                                        f16* lds, int t) {
#pragma unroll
  for (int p = 0; p < 4; ++p) {
    int L = p * 256 + t;          // 0..1023
    int row = L >> 3;
    int jp = L & 7;
    int jl = jp ^ (row & 7);
    g2l16(g0 + (size_t)row * stride + jl * 8, lds + L * 8);
  }
}
__device__ __forceinline__ f16x8 frag64(const f16* lds, int row, int kq) {
  int jp = (kq >> 3) ^ (row & 7);
  return *(const f16x8*)(lds + row * 64 + jp * 8);
}

// ---- 32x32x16 MFMA chunks. Wave tile 64x64 = 2x2 of 32x32.
// A/B per-lane: [m = lane&31][k = (lane>>5)*8 + j].
// C/D per-lane: col = lane&31, row = (reg&3) + 8*(reg>>2) + 4*(lane>>5).
__device__ __forceinline__ void chunk3_32(const f16* Ah, const f16* Al,
                                          const f16* Bh, const f16* Bl,
                                          fx16 acc[2][2], int wm, int wn, int lane) {
  const int r31 = lane & 31;
  const int kq = (lane >> 5) * 8;
#pragma unroll
  for (int k0 = 0; k0 < 32; k0 += 16) {
    f16x8 ah[2], al[2];
#pragma unroll
    for (int it = 0; it < 2; ++it) {
      int row = wm * 64 + it * 32 + r31;
      ah[it] = frag32(Ah, row, k0 + kq);
      al[it] = frag32(Al, row, k0 + kq);
    }
#pragma unroll
    for (int jt = 0; jt < 2; ++jt) {
      int col = wn * 64 + jt * 32 + r31;
      f16x8 bh = frag32(Bh, col, k0 + kq);
      f16x8 bl = frag32(Bl, col, k0 + kq);
#pragma unroll
      for (int it = 0; it < 2; ++it) {
        acc[it][jt] = __builtin_amdgcn_mfma_f32_32x32x16_f16(ah[it], bh, acc[it][jt], 0, 0, 0);
        acc[it][jt] = __builtin_amdgcn_mfma_f32_32x32x16_f16(ah[it], bl, acc[it][jt], 0, 0, 0);
        acc[it][jt] = __builtin_amdgcn_mfma_f32_32x32x16_f16(al[it], bh, acc[it][jt], 0, 0, 0);
      }
    }
  }
}

__device__ __forceinline__ void chunk1_64(const f16* A, const f16* B,
                                          fx16 acc[2][2], int wm, int wn, int lane) {
  const int r31 = lane & 31;
  const int kq = (lane >> 5) * 8;
#pragma unroll
  for (int k0 = 0; k0 < 64; k0 += 16) {
    f16x8 a[2];
#pragma unroll
    for (int it = 0; it < 2; ++it)
      a[it] = frag64(A, wm * 64 + it * 32 + r31, k0 + kq);
#pragma unroll
    for (int jt = 0; jt < 2; ++jt) {
      f16x8 b = frag64(B, wn * 64 + jt * 32 + r31, k0 + kq);
#pragma unroll
      for (int it = 0; it < 2; ++it)
        acc[it][jt] = __builtin_amdgcn_mfma_f32_32x32x16_f16(a[it], b, acc[it][jt], 0, 0, 0);
    }
  }
}

// ---------------------------------------------------------------------------
// Convert: x and Wq/Wk/Wv -> scaled split f16 (v*32 = hi + lo).
// ---------------------------------------------------------------------------
__global__ __launch_bounds__(256) void convert_split(
    const float* __restrict__ x, const float* __restrict__ Wq,
    const float* __restrict__ Wk, const float* __restrict__ Wv,
    f16* __restrict__ xh, f16* __restrict__ xl,
    f16* __restrict__ Wh, f16* __restrict__ Wl) {
  int idx = blockIdx.x * 256 + threadIdx.x;   // float4 index, 0..2293759
  const float* src; f16* dh; f16* dl; size_t off;
  if (idx < 2097152) { src = x; off = (size_t)idx; dh = xh; dl = xl; }
  else {
    int rr = idx - 2097152;
    int w = rr >> 16, o = rr & 65535;
    src = (w == 0) ? Wq : (w == 1) ? Wk : Wv;
    off = (size_t)o;
    dh = Wh + (size_t)w * 262144; dl = Wl + (size_t)w * 262144;
  }
  float4 v = ((const float4*)src)[off];
  float vv[4] = {v.x, v.y, v.z, v.w};
  f16x4 hv, lv;
#pragma unroll
  for (int i = 0; i < 4; ++i) {
    float s = vv[i] * 32.0f;
    f16 hi = (f16)s;
    hv[i] = hi;
    lv[i] = (f16)(s - (float)hi);
  }
  *(f16x4*)(dh + off * 4) = hv;
  *(f16x4*)(dl + off * 4) = lv;
}

// ---------------------------------------------------------------------------
// QKV, double-buffered (R0 structure): C = x*W^T + b. z=0 -> q split; z=1 ->
// k split (both 3-pass); z=2 -> v single f16 TRANSPOSED (1-pass).
// T1: XCD-chunked blockIdx swizzle (nwg=1536, chunk=192) so blocks sharing a
// W-panel / x-slice land on the same XCD's L2. Pure tile permutation.
// ---------------------------------------------------------------------------
__global__ __launch_bounds__(256) void qkv_mfma(
    const f16* __restrict__ xh, const f16* __restrict__ xl,
    const f16* __restrict__ Wh, const f16* __restrict__ Wl,
    const float* __restrict__ bq, const float* __restrict__ bk, const float* __restrict__ bv,
    f16* __restrict__ qh, f16* __restrict__ ql,
    f16* __restrict__ kh, f16* __restrict__ kl,
    f16* __restrict__ vt) {
  __shared__ __align__(16) f16 sm[32768];   // 64 KB = 2 x 32 KB buffers
  const int t = threadIdx.x;
  const int hw = blockIdx.x + (blockIdx.y << 7) + (blockIdx.z << 9);
  const int w  = (hw & 7) * 192 + (hw >> 3);          // bijective: 1536 % 8 == 0
  const int i0 = (w & 127) * 128;
  const int j0 = ((w >> 7) & 3) * 128;
  const int z  = w >> 9;
  const f16* WhZ = Wh + (size_t)z * 262144;
  const f16* WlZ = Wl + (size_t)z * 262144;
  const int lane = t & 63, wave = t >> 6;
  const int wm = wave >> 1, wn = wave & 1;
  const int r31 = lane & 31, half = lane >> 5;
  fx16 acc[2][2] = {};
  const f16* xhB = xh + (size_t)i0 * DM;
  const f16* xlB = xl + (size_t)i0 * DM;
  const f16* WhB = WhZ + (size_t)j0 * DM;
  const f16* WlB = WlZ + (size_t)j0 * DM;
  if (z < 2) {
    // prologue: chunk 0 into buf0
    stage32(xhB, DM, sm, t);
    stage32(xlB, DM, sm + 4096, t);
    stage32(WhB, DM, sm + 8192, t);
    stage32(WlB, DM, sm + 12288, t);
    __syncthreads();
    for (int c = 0; c < 16; ++c) {
      f16* cur = sm + (c & 1) * 16384;
      if (c < 15) {
        f16* nxt = sm + ((c + 1) & 1) * 16384;
        int d0 = (c + 1) * 32;
        stage32(xhB + d0, DM, nxt, t);
        stage32(xlB + d0, DM, nxt + 4096, t);
        stage32(WhB + d0, DM, nxt + 8192, t);
        stage32(WlB + d0, DM, nxt + 12288, t);
      }
      chunk3_32(cur, cur + 4096, cur + 8192, cur + 12288, acc, wm, wn, lane);
      if (c < 15) __syncthreads();
    }
  } else {
    stage64(xhB, DM, sm, t);
    stage64(WhB, DM, sm + 8192, t);
    __syncthreads();
    for (int c = 0; c < 8; ++c) {
      f16* cur = sm + (c & 1) * 16384;
      if (c < 7) {
        f16* nxt = sm + ((c + 1) & 1) * 16384;
        int d0 = (c + 1) * 64;
        stage64(xhB + d0, DM, nxt, t);
        stage64(WhB + d0, DM, nxt + 8192, t);
      }
      chunk1_64(cur, cur + 8192, acc, wm, wn, lane);
      if (c < 7) __syncthreads();
    }
  }
  const float* bias = (z == 0) ? bq : (z == 1) ? bk : bv;
  if (z < 2) {
    f16* oh = z ? kh : qh;  f16* ol = z ? kl : ql;
#pragma unroll
    for (int it = 0; it < 2; ++it)
#pragma unroll
      for (int jt = 0; jt < 2; ++jt) {
        int j = j0 + wn * 64 + jt * 32 + r31;
        float bj = bias[j];
#pragma unroll
        for (int r = 0; r < 16; ++r) {
          int ib = i0 + wm * 64 + it * 32 + (r & 3) + 8 * (r >> 2) + 4 * half;
          float val = acc[it][jt][r] * (1.0f / 1024.0f) + bj;   // exact f32 value
          float s = val * 32.0f;                                 // re-split, scaled
          f16 hi = (f16)s;
          oh[(size_t)ib * DM + j] = hi;
          ol[(size_t)ib * DM + j] = (f16)(s - (float)hi);
        }
      }
  } else {
#pragma unroll
    for (int it = 0; it < 2; ++it)
#pragma unroll
      for (int jt = 0; jt < 2; ++jt) {
        int j = j0 + wn * 64 + jt * 32 + r31;
        float bj = bias[j];
#pragma unroll
        for (int q4 = 0; q4 < 4; ++q4) {
          int ib = i0 + wm * 64 + it * 32 + 8 * q4 + 4 * half;   // 4 consecutive rows
          int bb = ib >> 11, nb = ib & 2047;
          f16x4 hv;
#pragma unroll
          for (int g = 0; g < 4; ++g)
            hv[g] = (f16)(acc[it][jt][q4 * 4 + g] * (1.0f / 1024.0f) + bj);
          *(f16x4*)(vt + ((size_t)(bb * DM + j)) * SEQ + nb) = hv;
        }
      }
  }
}

// ---------------------------------------------------------------------------
// Scores (EXACT R0 structure, proven 176 us / bit-exact): 3-pass split QK^T;
// aux single-f16 in the prologue (hides chunk-0 staging); merge+mask in f32;
// store S f16. T1: XCD-chunked swizzle (nwg=2048, chunk=256) — each XCD gets
// one batch; the 16 n-blocks sharing a kh/kl panel become L2-local.
// ---------------------------------------------------------------------------
__global__ __launch_bounds__(256) void scores_mfma(
    const f16* __restrict__ qh, const f16* __restrict__ ql,
    const f16* __restrict__ kh, const f16* __restrict__ kl,
    const float* __restrict__ qa, const float* __restrict__ ka,
    const int* __restrict__ adj,
    const float* __restrict__ mc_p, const float* __restrict__ thr_p,
    f16* __restrict__ S16) {
  __shared__ __align__(16) f16 sm[32768];   // 64 KB: buf0 | buf1 (aux uses buf1)
  const int t = threadIdx.x;
  const int hw = blockIdx.x + (blockIdx.y << 4) + (blockIdx.z << 8);
  const int w  = ((hw & 7) << 8) + (hw >> 3);         // bijective: 2048 % 8 == 0
  const int n0 = (w & 15) * 128;
  const int m0 = ((w >> 4) & 15) * 128;
  const int b  = w >> 8;
  const int lane = t & 63, wave = t >> 6;
  const int wm = wave >> 1, wn = wave & 1;
  const int r31 = lane & 31, half = lane >> 5;
  const int kq = half * 8;

  const f16* qhB = qh + ((size_t)b * SEQ + n0) * DM;
  const f16* qlB = ql + ((size_t)b * SEQ + n0) * DM;
  const f16* khB = kh + ((size_t)b * SEQ + m0) * DM;
  const f16* klB = kl + ((size_t)b * SEQ + m0) * DM;

  // ---- issue chunk-0 stage into buf0 (async; hidden behind aux phase) ----
  stage32(qhB, DM, sm, t);
  stage32(qlB, DM, sm + 4096, t);
  stage32(khB, DM, sm + 8192, t);
  stage32(klB, DM, sm + 12288, t);

  // ---- aux tiles into buf1 via plain stores ----
  f16* QAl = sm + 16384;   // [128][64] swizzled
  f16* KAl = sm + 24576;
  const float* QAb = qa + ((size_t)b * SEQ + n0) * DAUX;
  const float* KAb = ka + ((size_t)b * SEQ + m0) * DAUX;
#pragma unroll
  for (int p = 0; p < 4; ++p) {
    int L8 = p * 256 + t;
    int row = L8 >> 3, jb = L8 & 7;
    int c8 = jb * 8;
    int jp = jb ^ (row & 7);
    float4 u0 = *(const float4*)(QAb + (size_t)row * DAUX + c8);
    float4 u1 = *(const float4*)(QAb + (size_t)row * DAUX + c8 + 4);
    f16x8 hq = {(f16)u0.x,(f16)u0.y,(f16)u0.z,(f16)u0.w,(f16)u1.x,(f16)u1.y,(f16)u1.z,(f16)u1.w};
    *(f16x8*)(QAl + row * 64 + jp * 8) = hq;
    float4 w0 = *(const float4*)(KAb + (size_t)row * DAUX + c8);
    float4 w1 = *(const float4*)(KAb + (size_t)row * DAUX + c8 + 4);
    f16x8 hk = {(f16)w0.x,(f16)w0.y,(f16)w0.z,(f16)w0.w,(f16)w1.x,(f16)w1.y,(f16)w1.z,(f16)w1.w};
    *(f16x8*)(KAl + row * 64 + jp * 8) = hk;
  }
  __syncthreads();          // aux visible + chunk-0 loads drained

  // ---- aux MFMA phase (reads buf1) ----
  f16x2 sax2[2][2][8];
  {
    fx16 aacc[2][2] = {};
#pragma unroll
    for (int k0 = 0; k0 < 64; k0 += 16) {
      f16x8 qaf[2];
#pragma unroll
      for (int it = 0; it < 2; ++it)
        qaf[it] = frag64(QAl, wm * 64 + it * 32 + r31, k0 + kq);
#pragma unroll
      for (int jt = 0; jt < 2; ++jt) {
        f16x8 kaf = frag64(KAl, wn * 64 + jt * 32 + r31, k0 + kq);
#pragma unroll
        for (int it = 0; it < 2; ++it)
          aacc[it][jt] = __builtin_amdgcn_mfma_f32_32x32x16_f16(qaf[it], kaf, aacc[it][jt], 0, 0, 0);
      }
    }
#pragma unroll
    for (int it = 0; it < 2; ++it)
#pragma unroll
      for (int jt = 0; jt < 2; ++jt)
#pragma unroll
        for (int r = 0; r < 16; ++r)
          sax2[it][jt][r >> 1][r & 1] = (f16)aacc[it][jt][r];
  }
  __syncthreads();          // everyone done reading buf1 before c=0 prefetches into it

  // ---- main QK^T: 16 chunks, single barrier per chunk, prefetch-first ----
  fx16 acc[2][2] = {};
  for (int c = 0; c < 16; ++c) {
    f16* cur = sm + (c & 1) * 16384;
    if (c < 15) {
      f16* nxt = sm + ((c + 1) & 1) * 16384;
      int d0 = (c + 1) * 32;
      stage32(qhB + d0, DM, nxt, t);
      stage32(qlB + d0, DM, nxt + 4096, t);
      stage32(khB + d0, DM, nxt + 8192, t);
      stage32(klB + d0, DM, nxt + 12288, t);
    }
    chunk3_32(cur, cur + 4096, cur + 8192, cur + 12288, acc, wm, wn, lane);
    if (c < 15) __syncthreads();
  }

  // ---- merge + mask + f16 store ----
  const float mc = *mc_p, thr = *thr_p;
  const float invC = 1.0f / (1024.0f * 22.62741699796952f);  // /(32*32)/sqrt(512)
#pragma unroll
  for (int it = 0; it < 2; ++it)
#pragma unroll
    for (int jt = 0; jt < 2; ++jt) {
      int col = m0 + wn * 64 + jt * 32 + r31;
#pragma unroll
      for (int r = 0; r < 16; ++r) {
        int row = n0 + wm * 64 + it * 32 + (r & 3) + 8 * (r >> 2) + 4 * half;
        size_t rbase = ((size_t)b * SEQ + row) * SEQ;
        float s = acc[it][jt][r] * invC;
        float sa = (float)sax2[it][jt][r >> 1][r & 1] * 0.125f;
        if (sa != 0.0f && s > thr) s = (1.0f - mc) * s + mc * sa;
        if (adj[rbase + col] == 0) s = -65504.0f;   // f16 min -> exp()==0
        S16[rbase + col] = (f16)s;
      }
    }
}

// ---------------------------------------------------------------------------
// Softmax: one WAVE per row (4 rows/block, no barriers). In-place S16 row ->
// P16 = 1024*exp(s-max); rowsum = sum of the ROUNDED P16 (exact normalization).
// ---------------------------------------------------------------------------
__global__ __launch_bounds__(256) void softmax_p(
    f16* __restrict__ S16, float* __restrict__ rowsum) {
  const int wv = threadIdx.x >> 6, ln = threadIdx.x & 63;
  const size_t row = (size_t)blockIdx.x * 4 + wv;
  f16* Sr = S16 + row * SEQ;
  f16x8 v[4];
  float vals[32];
#pragma unroll
  for (int j = 0; j < 4; ++j) {
    v[j] = *(const f16x8*)(Sr + j * 512 + ln * 8);
#pragma unroll
    for (int i = 0; i < 8; ++i) vals[j * 8 + i] = (float)v[j][i];
  }
  float m = vals[0];
#pragma unroll
  for (int i = 1; i < 32; ++i) m = fmaxf(m, vals[i]);
#pragma unroll
  for (int off = 1; off < 64; off <<= 1) m = fmaxf(m, __shfl_xor(m, off, 64));
  float z = 0.f;
  f16x8 p16[4];
#pragma unroll
  for (int j = 0; j < 4; ++j)
#pragma unroll
    for (int i = 0; i < 8; ++i) {
      f16 p = (f16)(__expf(vals[j * 8 + i] - m) * 1024.0f);
      p16[j][i] = p;
      z += (float)p;
    }
#pragma unroll
  for (int off = 1; off < 64; off <<= 1) z += __shfl_xor(z, off, 64);
  if (ln == 0) rowsum[row] = z;
#pragma unroll
  for (int j = 0; j < 4; ++j)
    *(f16x8*)(Sr + j * 512 + ln * 8) = p16[j];
}

// ---------------------------------------------------------------------------
// PV, double-buffered (R0 structure): O[n][d] = (sum_m P16[n][m]*vt[d][m]) /
// rowsum[n]. T1: XCD-chunked swizzle (nwg=512, chunk=64) — each XCD gets one
// batch; d-blocks sharing P-rows and n-blocks sharing V-panels become L2-local.
// ---------------------------------------------------------------------------
__global__ __launch_bounds__(256) void pv_mfma(
    const f16* __restrict__ P16, const f16* __restrict__ vt,
    const float* __restrict__ rowsum, float* __restrict__ O) {
  __shared__ __align__(16) f16 sm[32768];   // 64 KB = 2 x (Ps 16KB + Vs 16KB)
  const int t = threadIdx.x;
  const int hw = blockIdx.x + (blockIdx.y << 4) + (blockIdx.z << 6);
  const int w  = ((hw & 7) << 6) + (hw >> 3);         // bijective: 512 % 8 == 0
  const int n0 = (w & 15) * 128;
  const int d0 = ((w >> 4) & 3) * 128;
  const int b  = w >> 6;
  const int lane = t & 63, wave = t >> 6;
  const int wm = wave >> 1, wn = wave & 1;
  const int r31 = lane & 31, half = lane >> 5;
  fx16 acc[2][2] = {};
  const f16* Pb = P16 + ((size_t)b * SEQ + n0) * SEQ;
  const f16* Vb = vt + ((size_t)b * DM + d0) * SEQ;
  stage64(Pb, SEQ, sm, t);
  stage64(Vb, SEQ, sm + 8192, t);
  __syncthreads();
  for (int c = 0; c < 32; ++c) {
    f16* cur = sm + (c & 1) * 16384;
    if (c < 31) {
      f16* nxt = sm + ((c + 1) & 1) * 16384;
      int m0 = (c + 1) * 64;
      stage64(Pb + m0, SEQ, nxt, t);
      stage64(Vb + m0, SEQ, nxt + 8192, t);
    }
    chunk1_64(cur, cur + 8192, acc, wm, wn, lane);
    if (c < 31) __syncthreads();
  }
#pragma unroll
  for (int it = 0; it < 2; ++it)
#pragma unroll
    for (int jt = 0; jt < 2; ++jt) {
      int d = d0 + wn * 64 + jt * 32 + r31;
#pragma unroll
      for (int r = 0; r < 16; ++r) {
        int n = n0 + wm * 64 + it * 32 + (r & 3) + 8 * (r >> 2) + 4 * half;
        float inv = 1.0f / rowsum[(size_t)b * SEQ + n];
        O[((size_t)b * SEQ + n) * DM + d] = acc[it][jt][r] * inv;
      }
    }
}

// ---------------------------------------------------------------------------
extern "C" void kernel_launch(void* const* d_in, const int* in_sizes, int n_in,
                              void* d_out, int out_size, void* d_ws, size_t ws_size,
                              hipStream_t stream) {
  const float* x   = (const float*)d_in[0];
  const float* qa  = (const float*)d_in[1];
  const float* ka  = (const float*)d_in[2];
  const int*   adj = (const int*)d_in[3];
  const float* mc  = (const float*)d_in[4];
  const float* Wq  = (const float*)d_in[5];
  const float* bq  = (const float*)d_in[6];
  const float* Wk  = (const float*)d_in[7];
  const float* bk  = (const float*)d_in[8];
  const float* Wv  = (const float*)d_in[9];
  const float* bv  = (const float*)d_in[10];
  const float* thr = (const float*)d_in[11];
  float* out = (float*)d_out;

  // ws layout (f16 elems): qh|ql|kh|kl|vt (8.39M each) | S16 (33.55M) | rowsum
  // convert outputs xh/xl/Wh/Wl alias the S16 region (dead before S16 written).
  f16* qh  = (f16*)d_ws;
  f16* ql  = qh + 8388608;
  f16* kh  = ql + 8388608;
  f16* kl  = kh + 8388608;
  f16* vt  = kl + 8388608;
  f16* S16 = vt + 8388608;
  float* rowsum = (float*)(S16 + 33554432);
  f16* xh = S16;                 // alias
  f16* xl = xh + 8388608;
  f16* Wh = xl + 8388608;        // [3][512*512]
  f16* Wl = Wh + 786432;

  convert_split<<<8960, 256, 0, stream>>>(x, Wq, Wk, Wv, xh, xl, Wh, Wl);
  qkv_mfma<<<dim3(128, 4, 3), 256, 0, stream>>>(xh, xl, Wh, Wl, bq, bk, bv,
                                                qh, ql, kh, kl, vt);
  scores_mfma<<<dim3(16, 16, 8), 256, 0, stream>>>(qh, ql, kh, kl, qa, ka, adj,
                                                   mc, thr, S16);
  softmax_p<<<4096, 256, 0, stream>>>(S16, rowsum);
  pv_mfma<<<dim3(16, 4, 8), 256, 0, stream>>>(S16, vt, rowsum, out);
}

// Round 8
// 503.210 us; speedup vs baseline: 1.1166x; 1.0783x over previous
//
#include <hip/hip_runtime.h>
#include <cstdint>

#define SEQ    2048
#define DM     512
#define DAUX   64

typedef _Float16 f16;
typedef __attribute__((ext_vector_type(2))) _Float16 f16x2;
typedef __attribute__((ext_vector_type(4))) _Float16 f16x4;
typedef __attribute__((ext_vector_type(8))) _Float16 f16x8;
typedef __attribute__((ext_vector_type(4))) float fx4;
typedef __attribute__((ext_vector_type(16))) float fx16;

// async global->LDS, 16B per lane. LDS dest must be wave-uniform base + lane*16.
__device__ __forceinline__ void g2l16(const void* g, void* l) {
  __builtin_amdgcn_global_load_lds(
      (__attribute__((address_space(1))) void*)const_cast<void*>(g),
      (__attribute__((address_space(3))) void*)l, 16, 0, 0);
}

// ---- BK=32 tile [128][32], XOR swizzle on 8-elem blocks (jp ^ (row>>1)&3).
__device__ __forceinline__ void stage32(const f16* __restrict__ g0, int stride,
                                        f16* lds, int t) {
#pragma unroll
  for (int p = 0; p < 2; ++p) {
    int L = p * 256 + t;          // 0..511
    int row = L >> 2;             // 0..127
    int jp = L & 3;
    int jl = jp ^ ((row >> 1) & 3);
    g2l16(g0 + (size_t)row * stride + jl * 8, lds + L * 8);
  }
}
__device__ __forceinline__ f16x8 frag32(const f16* lds, int row, int kq) {
  int jp = (kq >> 3) ^ ((row >> 1) & 3);
  return *(const f16x8*)(lds + row * 32 + jp * 8);
}

// ---- BK=64 tile [128][64], swizzle jp ^ (row&7) (measured conflict-free).
__device__ __forceinline__ void stage64(const f16* __restrict__ g0, int stride,
                                        f16* lds, int t) {
#pragma unroll
  for (int p = 0; p < 4; ++p) {
    int L = p * 256 + t;          // 0..1023
    int row = L >> 3;
    int jp = L & 7;
    int jl = jp ^ (row & 7);
    g2l16(g0 + (size_t)row * stride + jl * 8, lds + L * 8);
  }
}
__device__ __forceinline__ f16x8 frag64(const f16* lds, int row, int kq) {
  int jp = (kq >> 3) ^ (row & 7);
  return *(const f16x8*)(lds + row * 64 + jp * 8);
}

// ---- 32x32x16 MFMA chunks. Wave tile 64x64 = 2x2 of 32x32.
// A/B per-lane: [m = lane&31][k = (lane>>5)*8 + j].
// C/D per-lane: col = lane&31, row = (reg&3) + 8*(reg>>2) + 4*(lane>>5).
__device__ __forceinline__ void chunk3_32(const f16* Ah, const f16* Al,
                                          const f16* Bh, const f16* Bl,
                                          fx16 acc[2][2], int wm, int wn, int lane) {
  const int r31 = lane & 31;
  const int kq = (lane >> 5) * 8;
#pragma unroll
  for (int k0 = 0; k0 < 32; k0 += 16) {
    f16x8 ah[2], al[2];
#pragma unroll
    for (int it = 0; it < 2; ++it) {
      int row = wm * 64 + it * 32 + r31;
      ah[it] = frag32(Ah, row, k0 + kq);
      al[it] = frag32(Al, row, k0 + kq);
    }
#pragma unroll
    for (int jt = 0; jt < 2; ++jt) {
      int col = wn * 64 + jt * 32 + r31;
      f16x8 bh = frag32(Bh, col, k0 + kq);
      f16x8 bl = frag32(Bl, col, k0 + kq);
#pragma unroll
      for (int it = 0; it < 2; ++it) {
        acc[it][jt] = __builtin_amdgcn_mfma_f32_32x32x16_f16(ah[it], bh, acc[it][jt], 0, 0, 0);
        acc[it][jt] = __builtin_amdgcn_mfma_f32_32x32x16_f16(ah[it], bl, acc[it][jt], 0, 0, 0);
        acc[it][jt] = __builtin_amdgcn_mfma_f32_32x32x16_f16(al[it], bh, acc[it][jt], 0, 0, 0);
      }
    }
  }
}

__device__ __forceinline__ void chunk1_64(const f16* A, const f16* B,
                                          fx16 acc[2][2], int wm, int wn, int lane) {
  const int r31 = lane & 31;
  const int kq = (lane >> 5) * 8;
#pragma unroll
  for (int k0 = 0; k0 < 64; k0 += 16) {
    f16x8 a[2];
#pragma unroll
    for (int it = 0; it < 2; ++it)
      a[it] = frag64(A, wm * 64 + it * 32 + r31, k0 + kq);
#pragma unroll
    for (int jt = 0; jt < 2; ++jt) {
      f16x8 b = frag64(B, wn * 64 + jt * 32 + r31, k0 + kq);
#pragma unroll
      for (int it = 0; it < 2; ++it)
        acc[it][jt] = __builtin_amdgcn_mfma_f32_32x32x16_f16(a[it], b, acc[it][jt], 0, 0, 0);
    }
  }
}

// ---------------------------------------------------------------------------
// Convert: x and Wq/Wk/Wv -> scaled split f16 (v*32 = hi + lo).
// ---------------------------------------------------------------------------
__global__ __launch_bounds__(256) void convert_split(
    const float* __restrict__ x, const float* __restrict__ Wq,
    const float* __restrict__ Wk, const float* __restrict__ Wv,
    f16* __restrict__ xh, f16* __restrict__ xl,
    f16* __restrict__ Wh, f16* __restrict__ Wl) {
  int idx = blockIdx.x * 256 + threadIdx.x;   // float4 index, 0..2293759
  const float* src; f16* dh; f16* dl; size_t off;
  if (idx < 2097152) { src = x; off = (size_t)idx; dh = xh; dl = xl; }
  else {
    int rr = idx - 2097152;
    int w = rr >> 16, o = rr & 65535;
    src = (w == 0) ? Wq : (w == 1) ? Wk : Wv;
    off = (size_t)o;
    dh = Wh + (size_t)w * 262144; dl = Wl + (size_t)w * 262144;
  }
  float4 v = ((const float4*)src)[off];
  float vv[4] = {v.x, v.y, v.z, v.w};
  f16x4 hv, lv;
#pragma unroll
  for (int i = 0; i < 4; ++i) {
    float s = vv[i] * 32.0f;
    f16 hi = (f16)s;
    hv[i] = hi;
    lv[i] = (f16)(s - (float)hi);
  }
  *(f16x4*)(dh + off * 4) = hv;
  *(f16x4*)(dl + off * 4) = lv;
}

// ---------------------------------------------------------------------------
// QKV, double-buffered (EXACT R0, natural block order): C = x*W^T + b.
// z=0 -> q split; z=1 -> k split (both 3-pass); z=2 -> v single f16
// TRANSPOSED (1-pass). Natural order already makes all 12 reuses of each
// x row-block (32 MB array) XCD-local (hw%8 = i-block%8) — R7's swizzle
// traded that for W locality (1.5 MB/panel) and regressed; reverted.
// ---------------------------------------------------------------------------
__global__ __launch_bounds__(256) void qkv_mfma(
    const f16* __restrict__ xh, const f16* __restrict__ xl,
    const f16* __restrict__ Wh, const f16* __restrict__ Wl,
    const float* __restrict__ bq, const float* __restrict__ bk, const float* __restrict__ bv,
    f16* __restrict__ qh, f16* __restrict__ ql,
    f16* __restrict__ kh, f16* __restrict__ kl,
    f16* __restrict__ vt) {
  __shared__ __align__(16) f16 sm[32768];   // 64 KB = 2 x 32 KB buffers
  const int t = threadIdx.x;
  const int i0 = blockIdx.x * 128, j0 = blockIdx.y * 128, z = blockIdx.z;
  const f16* WhZ = Wh + (size_t)z * 262144;
  const f16* WlZ = Wl + (size_t)z * 262144;
  const int lane = t & 63, wave = t >> 6;
  const int wm = wave >> 1, wn = wave & 1;
  const int r31 = lane & 31, half = lane >> 5;
  fx16 acc[2][2] = {};
  const f16* xhB = xh + (size_t)i0 * DM;
  const f16* xlB = xl + (size_t)i0 * DM;
  const f16* WhB = WhZ + (size_t)j0 * DM;
  const f16* WlB = WlZ + (size_t)j0 * DM;
  if (z < 2) {
    // prologue: chunk 0 into buf0
    stage32(xhB, DM, sm, t);
    stage32(xlB, DM, sm + 4096, t);
    stage32(WhB, DM, sm + 8192, t);
    stage32(WlB, DM, sm + 12288, t);
    __syncthreads();
    for (int c = 0; c < 16; ++c) {
      f16* cur = sm + (c & 1) * 16384;
      if (c < 15) {
        f16* nxt = sm + ((c + 1) & 1) * 16384;
        int d0 = (c + 1) * 32;
        stage32(xhB + d0, DM, nxt, t);
        stage32(xlB + d0, DM, nxt + 4096, t);
        stage32(WhB + d0, DM, nxt + 8192, t);
        stage32(WlB + d0, DM, nxt + 12288, t);
      }
      chunk3_32(cur, cur + 4096, cur + 8192, cur + 12288, acc, wm, wn, lane);
      if (c < 15) __syncthreads();
    }
  } else {
    stage64(xhB, DM, sm, t);
    stage64(WhB, DM, sm + 8192, t);
    __syncthreads();
    for (int c = 0; c < 8; ++c) {
      f16* cur = sm + (c & 1) * 16384;
      if (c < 7) {
        f16* nxt = sm + ((c + 1) & 1) * 16384;
        int d0 = (c + 1) * 64;
        stage64(xhB + d0, DM, nxt, t);
        stage64(WhB + d0, DM, nxt + 8192, t);
      }
      chunk1_64(cur, cur + 8192, acc, wm, wn, lane);
      if (c < 7) __syncthreads();
    }
  }
  const float* bias = (z == 0) ? bq : (z == 1) ? bk : bv;
  if (z < 2) {
    f16* oh = z ? kh : qh;  f16* ol = z ? kl : ql;
#pragma unroll
    for (int it = 0; it < 2; ++it)
#pragma unroll
      for (int jt = 0; jt < 2; ++jt) {
        int j = j0 + wn * 64 + jt * 32 + r31;
        float bj = bias[j];
#pragma unroll
        for (int r = 0; r < 16; ++r) {
          int ib = i0 + wm * 64 + it * 32 + (r & 3) + 8 * (r >> 2) + 4 * half;
          float val = acc[it][jt][r] * (1.0f / 1024.0f) + bj;   // exact f32 value
          float s = val * 32.0f;                                 // re-split, scaled
          f16 hi = (f16)s;
          oh[(size_t)ib * DM + j] = hi;
          ol[(size_t)ib * DM + j] = (f16)(s - (float)hi);
        }
      }
  } else {
#pragma unroll
    for (int it = 0; it < 2; ++it)
#pragma unroll
      for (int jt = 0; jt < 2; ++jt) {
        int j = j0 + wn * 64 + jt * 32 + r31;
        float bj = bias[j];
#pragma unroll
        for (int q4 = 0; q4 < 4; ++q4) {
          int ib = i0 + wm * 64 + it * 32 + 8 * q4 + 4 * half;   // 4 consecutive rows
          int bb = ib >> 11, nb = ib & 2047;
          f16x4 hv;
#pragma unroll
          for (int g = 0; g < 4; ++g)
            hv[g] = (f16)(acc[it][jt][q4 * 4 + g] * (1.0f / 1024.0f) + bj);
          *(f16x4*)(vt + ((size_t)(bb * DM + j)) * SEQ + nb) = hv;
        }
      }
  }
}

// ---------------------------------------------------------------------------
// Scores (R0 structure, proven 176 us / bit-exact; R7's XCD swizzle kept:
// time-neutral, FETCH 232->196 MB). 3-pass split QK^T; aux single-f16 in the
// prologue (hides chunk-0 staging); merge+mask in f32; store S f16.
// ---------------------------------------------------------------------------
__global__ __launch_bounds__(256) void scores_mfma(
    const f16* __restrict__ qh, const f16* __restrict__ ql,
    const f16* __restrict__ kh, const f16* __restrict__ kl,
    const float* __restrict__ qa, const float* __restrict__ ka,
    const int* __restrict__ adj,
    const float* __restrict__ mc_p, const float* __restrict__ thr_p,
    f16* __restrict__ S16) {
  __shared__ __align__(16) f16 sm[32768];   // 64 KB: buf0 | buf1 (aux uses buf1)
  const int t = threadIdx.x;
  const int hw = blockIdx.x + (blockIdx.y << 4) + (blockIdx.z << 8);
  const int w  = ((hw & 7) << 8) + (hw >> 3);         // bijective: 2048 % 8 == 0
  const int n0 = (w & 15) * 128;
  const int m0 = ((w >> 4) & 15) * 128;
  const int b  = w >> 8;
  const int lane = t & 63, wave = t >> 6;
  const int wm = wave >> 1, wn = wave & 1;
  const int r31 = lane & 31, half = lane >> 5;
  const int kq = half * 8;

  const f16* qhB = qh + ((size_t)b * SEQ + n0) * DM;
  const f16* qlB = ql + ((size_t)b * SEQ + n0) * DM;
  const f16* khB = kh + ((size_t)b * SEQ + m0) * DM;
  const f16* klB = kl + ((size_t)b * SEQ + m0) * DM;

  // ---- issue chunk-0 stage into buf0 (async; hidden behind aux phase) ----
  stage32(qhB, DM, sm, t);
  stage32(qlB, DM, sm + 4096, t);
  stage32(khB, DM, sm + 8192, t);
  stage32(klB, DM, sm + 12288, t);

  // ---- aux tiles into buf1 via plain stores ----
  f16* QAl = sm + 16384;   // [128][64] swizzled
  f16* KAl = sm + 24576;
  const float* QAb = qa + ((size_t)b * SEQ + n0) * DAUX;
  const float* KAb = ka + ((size_t)b * SEQ + m0) * DAUX;
#pragma unroll
  for (int p = 0; p < 4; ++p) {
    int L8 = p * 256 + t;
    int row = L8 >> 3, jb = L8 & 7;
    int c8 = jb * 8;
    int jp = jb ^ (row & 7);
    float4 u0 = *(const float4*)(QAb + (size_t)row * DAUX + c8);
    float4 u1 = *(const float4*)(QAb + (size_t)row * DAUX + c8 + 4);
    f16x8 hq = {(f16)u0.x,(f16)u0.y,(f16)u0.z,(f16)u0.w,(f16)u1.x,(f16)u1.y,(f16)u1.z,(f16)u1.w};
    *(f16x8*)(QAl + row * 64 + jp * 8) = hq;
    float4 w0 = *(const float4*)(KAb + (size_t)row * DAUX + c8);
    float4 w1 = *(const float4*)(KAb + (size_t)row * DAUX + c8 + 4);
    f16x8 hk = {(f16)w0.x,(f16)w0.y,(f16)w0.z,(f16)w0.w,(f16)w1.x,(f16)w1.y,(f16)w1.z,(f16)w1.w};
    *(f16x8*)(KAl + row * 64 + jp * 8) = hk;
  }
  __syncthreads();          // aux visible + chunk-0 loads drained

  // ---- aux MFMA phase (reads buf1) ----
  f16x2 sax2[2][2][8];
  {
    fx16 aacc[2][2] = {};
#pragma unroll
    for (int k0 = 0; k0 < 64; k0 += 16) {
      f16x8 qaf[2];
#pragma unroll
      for (int it = 0; it < 2; ++it)
        qaf[it] = frag64(QAl, wm * 64 + it * 32 + r31, k0 + kq);
#pragma unroll
      for (int jt = 0; jt < 2; ++jt) {
        f16x8 kaf = frag64(KAl, wn * 64 + jt * 32 + r31, k0 + kq);
#pragma unroll
        for (int it = 0; it < 2; ++it)
          aacc[it][jt] = __builtin_amdgcn_mfma_f32_32x32x16_f16(qaf[it], kaf, aacc[it][jt], 0, 0, 0);
      }
    }
#pragma unroll
    for (int it = 0; it < 2; ++it)
#pragma unroll
      for (int jt = 0; jt < 2; ++jt)
#pragma unroll
        for (int r = 0; r < 16; ++r)
          sax2[it][jt][r >> 1][r & 1] = (f16)aacc[it][jt][r];
  }
  __syncthreads();          // everyone done reading buf1 before c=0 prefetches into it

  // ---- main QK^T: 16 chunks, single barrier per chunk, prefetch-first ----
  fx16 acc[2][2] = {};
  for (int c = 0; c < 16; ++c) {
    f16* cur = sm + (c & 1) * 16384;
    if (c < 15) {
      f16* nxt = sm + ((c + 1) & 1) * 16384;
      int d0 = (c + 1) * 32;
      stage32(qhB + d0, DM, nxt, t);
      stage32(qlB + d0, DM, nxt + 4096, t);
      stage32(khB + d0, DM, nxt + 8192, t);
      stage32(klB + d0, DM, nxt + 12288, t);
    }
    chunk3_32(cur, cur + 4096, cur + 8192, cur + 12288, acc, wm, wn, lane);
    if (c < 15) __syncthreads();
  }

  // ---- merge + mask + f16 store ----
  const float mc = *mc_p, thr = *thr_p;
  const float invC = 1.0f / (1024.0f * 22.62741699796952f);  // /(32*32)/sqrt(512)
#pragma unroll
  for (int it = 0; it < 2; ++it)
#pragma unroll
    for (int jt = 0; jt < 2; ++jt) {
      int col = m0 + wn * 64 + jt * 32 + r31;
#pragma unroll
      for (int r = 0; r < 16; ++r) {
        int row = n0 + wm * 64 + it * 32 + (r & 3) + 8 * (r >> 2) + 4 * half;
        size_t rbase = ((size_t)b * SEQ + row) * SEQ;
        float s = acc[it][jt][r] * invC;
        float sa = (float)sax2[it][jt][r >> 1][r & 1] * 0.125f;
        if (sa != 0.0f && s > thr) s = (1.0f - mc) * s + mc * sa;
        if (adj[rbase + col] == 0) s = -65504.0f;   // f16 min -> exp()==0
        S16[rbase + col] = (f16)s;
      }
    }
}

// ---------------------------------------------------------------------------
// Softmax: one WAVE per row (4 rows/block, no barriers). In-place S16 row ->
// P16 = 1024*exp(s-max); rowsum = sum of the ROUNDED P16 (exact normalization).
// ---------------------------------------------------------------------------
__global__ __launch_bounds__(256) void softmax_p(
    f16* __restrict__ S16, float* __restrict__ rowsum) {
  const int wv = threadIdx.x >> 6, ln = threadIdx.x & 63;
  const size_t row = (size_t)blockIdx.x * 4 + wv;
  f16* Sr = S16 + row * SEQ;
  f16x8 v[4];
  float vals[32];
#pragma unroll
  for (int j = 0; j < 4; ++j) {
    v[j] = *(const f16x8*)(Sr + j * 512 + ln * 8);
#pragma unroll
    for (int i = 0; i < 8; ++i) vals[j * 8 + i] = (float)v[j][i];
  }
  float m = vals[0];
#pragma unroll
  for (int i = 1; i < 32; ++i) m = fmaxf(m, vals[i]);
#pragma unroll
  for (int off = 1; off < 64; off <<= 1) m = fmaxf(m, __shfl_xor(m, off, 64));
  float z = 0.f;
  f16x8 p16[4];
#pragma unroll
  for (int j = 0; j < 4; ++j)
#pragma unroll
    for (int i = 0; i < 8; ++i) {
      f16 p = (f16)(__expf(vals[j * 8 + i] - m) * 1024.0f);
      p16[j][i] = p;
      z += (float)p;
    }
#pragma unroll
  for (int off = 1; off < 64; off <<= 1) z += __shfl_xor(z, off, 64);
  if (ln == 0) rowsum[row] = z;
#pragma unroll
  for (int j = 0; j < 4; ++j)
    *(f16x8*)(Sr + j * 512 + ln * 8) = p16[j];
}

// ---------------------------------------------------------------------------
// PV, double-buffered (R0 structure): O[n][d] = (sum_m P16[n][m]*vt[d][m]) /
// rowsum[n]. T1 swizzle, CORRECTED inner order vs R7: b = hw&7 pins batch to
// XCD (P+V working set 10 MB/XCD); d0 FASTEST so each P row-block is read by
// 4 consecutive blocks (L2-hot, fetched once) while the 4 V panels (2 MB)
// stay resident. R7 had n0 fastest -> P reuse distance 16 (8 MB > L2).
// ---------------------------------------------------------------------------
__global__ __launch_bounds__(256) void pv_mfma(
    const f16* __restrict__ P16, const f16* __restrict__ vt,
    const float* __restrict__ rowsum, float* __restrict__ O) {
  __shared__ __align__(16) f16 sm[32768];   // 64 KB = 2 x (Ps 16KB + Vs 16KB)
  const int t = threadIdx.x;
  const int hw = blockIdx.x + (blockIdx.y << 4) + (blockIdx.z << 6);
  const int b  = hw & 7;            // XCD-pinned batch
  const int q  = hw >> 3;           // 0..63
  const int d0 = (q & 3) * 128;     // fastest: V panels cycle, stay L2-resident
  const int n0 = (q >> 2) * 128;    // P row-block advances every 4 blocks
  const int lane = t & 63, wave = t >> 6;
  const int wm = wave >> 1, wn = wave & 1;
  const int r31 = lane & 31, half = lane >> 5;
  fx16 acc[2][2] = {};
  const f16* Pb = P16 + ((size_t)b * SEQ + n0) * SEQ;
  const f16* Vb = vt + ((size_t)b * DM + d0) * SEQ;
  stage64(Pb, SEQ, sm, t);
  stage64(Vb, SEQ, sm + 8192, t);
  __syncthreads();
  for (int c = 0; c < 32; ++c) {
    f16* cur = sm + (c & 1) * 16384;
    if (c < 31) {
      f16* nxt = sm + ((c + 1) & 1) * 16384;
      int m0 = (c + 1) * 64;
      stage64(Pb + m0, SEQ, nxt, t);
      stage64(Vb + m0, SEQ, nxt + 8192, t);
    }
    chunk1_64(cur, cur + 8192, acc, wm, wn, lane);
    if (c < 31) __syncthreads();
  }
#pragma unroll
  for (int it = 0; it < 2; ++it)
#pragma unroll
    for (int jt = 0; jt < 2; ++jt) {
      int d = d0 + wn * 64 + jt * 32 + r31;
#pragma unroll
      for (int r = 0; r < 16; ++r) {
        int n = n0 + wm * 64 + it * 32 + (r & 3) + 8 * (r >> 2) + 4 * half;
        float inv = 1.0f / rowsum[(size_t)b * SEQ + n];
        O[((size_t)b * SEQ + n) * DM + d] = acc[it][jt][r] * inv;
      }
    }
}

// ---------------------------------------------------------------------------
extern "C" void kernel_launch(void* const* d_in, const int* in_sizes, int n_in,
                              void* d_out, int out_size, void* d_ws, size_t ws_size,
                              hipStream_t stream) {
  const float* x   = (const float*)d_in[0];
  const float* qa  = (const float*)d_in[1];
  const float* ka  = (const float*)d_in[2];
  const int*   adj = (const int*)d_in[3];
  const float* mc  = (const float*)d_in[4];
  const float* Wq  = (const float*)d_in[5];
  const float* bq  = (const float*)d_in[6];
  const float* Wk  = (const float*)d_in[7];
  const float* bk  = (const float*)d_in[8];
  const float* Wv  = (const float*)d_in[9];
  const float* bv  = (const float*)d_in[10];
  const float* thr = (const float*)d_in[11];
  float* out = (float*)d_out;

  // ws layout (f16 elems): qh|ql|kh|kl|vt (8.39M each) | S16 (33.55M) | rowsum
  // convert outputs xh/xl/Wh/Wl alias the S16 region (dead before S16 written).
  f16* qh  = (f16*)d_ws;
  f16* ql  = qh + 8388608;
  f16* kh  = ql + 8388608;
  f16* kl  = kh + 8388608;
  f16* vt  = kl + 8388608;
  f16* S16 = vt + 8388608;
  float* rowsum = (float*)(S16 + 33554432);
  f16* xh = S16;                 // alias
  f16* xl = xh + 8388608;
  f16* Wh = xl + 8388608;        // [3][512*512]
  f16* Wl = Wh + 786432;

  convert_split<<<8960, 256, 0, stream>>>(x, Wq, Wk, Wv, xh, xl, Wh, Wl);
  qkv_mfma<<<dim3(128, 4, 3), 256, 0, stream>>>(xh, xl, Wh, Wl, bq, bk, bv,
                                                qh, ql, kh, kl, vt);
  scores_mfma<<<dim3(16, 16, 8), 256, 0, stream>>>(qh, ql, kh, kl, qa, ka, adj,
                                                   mc, thr, S16);
  softmax_p<<<4096, 256, 0, stream>>>(S16, rowsum);
  pv_mfma<<<dim3(16, 4, 8), 256, 0, stream>>>(S16, vt, rowsum, out);
}